// Round 6
// baseline (609.999 us; speedup 1.0000x reference)
//
#include <hip/hip_runtime.h>
#include <hip/hip_bf16.h>

#define T_LEN 1024
#define HID 1024
#define NH 32
#define HD 64
#define DIMC 2048
#define CONVD 2304
#define PROJ_C 4864
#define DST 128
#define NLV 15

typedef __attribute__((ext_vector_type(8))) short bf16x8;
typedef __attribute__((ext_vector_type(4))) float f32x4;

__device__ __forceinline__ float bf2f(short s) {
  unsigned u = ((unsigned)(unsigned short)s) << 16;
  return __builtin_bit_cast(float, u);
}
__device__ __forceinline__ short f2bf(float f) {
  return __builtin_bit_cast(short, __float2bfloat16(f));
}
__device__ __forceinline__ void gload16(const void* g, void* l) {
  __builtin_amdgcn_global_load_lds((const __attribute__((address_space(1))) unsigned int*)g,
                                   (__attribute__((address_space(3))) unsigned int*)l, 16, 0, 0);
}
__device__ __forceinline__ float softplus_f(float x) {
  return (x > 15.f) ? x : log1pf(expf(x));
}

// ---------------- split f32 -> bf16 hi + lo (Dekker) ----------------
__global__ void cast_split_kernel(const float* __restrict__ in,
    unsigned short* __restrict__ hi, unsigned short* __restrict__ lo, int n) {
  int i = (blockIdx.x * 256 + threadIdx.x) * 4;
  if (i >= n) return;
  float4 v = *(const float4*)(in + i);
  ushort4 h, l;
  h.x = (unsigned short)f2bf(v.x); l.x = (unsigned short)f2bf(v.x - bf2f((short)h.x));
  h.y = (unsigned short)f2bf(v.y); l.y = (unsigned short)f2bf(v.y - bf2f((short)h.y));
  h.z = (unsigned short)f2bf(v.z); l.z = (unsigned short)f2bf(v.z - bf2f((short)h.z));
  h.w = (unsigned short)f2bf(v.w); l.w = (unsigned short)f2bf(v.w - bf2f((short)h.w));
  *(ushort4*)(hi + i) = h;
  *(ushort4*)(lo + i) = l;
}

// ------- bf16 MFMA GEMM: C[M,N] = [C +] A[M,K]*B[N,K]^T [+ bias] -------
template<int OUT_BF16, int HAS_BIAS, int ACC_IN>
__global__ __launch_bounds__(256) void gemm_bt(const unsigned short* __restrict__ A,
    const unsigned short* __restrict__ B, const float* __restrict__ bias,
    void* __restrict__ C, int M, int N, int K) {
  __shared__ __align__(16) unsigned short As[128 * 64];
  __shared__ __align__(16) unsigned short Bs[128 * 64];
  const int tid = threadIdx.x;
  const int lane = tid & 63, wave = tid >> 6;
  const int wm = wave >> 1, wn = wave & 1;
  const int lrow = lane & 15, lgrp = lane >> 4;
  const int row0 = blockIdx.y * 128, col0 = blockIdx.x * 128;
  f32x4 zero4 = {0.f, 0.f, 0.f, 0.f};
  f32x4 acc[4][4];
  for (int i = 0; i < 4; ++i) for (int j = 0; j < 4; ++j) acc[i][j] = zero4;

  for (int k0 = 0; k0 < K; k0 += 64) {
#pragma unroll
    for (int it = 0; it < 4; ++it) {
      int e = (it * 256 + tid) * 8;
      int r = e >> 6, c = e & 63;
      gload16(A + (size_t)(row0 + r) * K + k0 + c, As + it * 2048 + wave * 512);
      gload16(B + (size_t)(col0 + r) * K + k0 + c, Bs + it * 2048 + wave * 512);
    }
    __syncthreads();
#pragma unroll
    for (int kk = 0; kk < 2; ++kk) {
      bf16x8 af[4], bfv[4];
#pragma unroll
      for (int i = 0; i < 4; ++i)
        af[i] = *(const bf16x8*)(As + (wm * 64 + i * 16 + lrow) * 64 + kk * 32 + lgrp * 8);
#pragma unroll
      for (int j = 0; j < 4; ++j)
        bfv[j] = *(const bf16x8*)(Bs + (wn * 64 + j * 16 + lrow) * 64 + kk * 32 + lgrp * 8);
#pragma unroll
      for (int i = 0; i < 4; ++i)
#pragma unroll
        for (int j = 0; j < 4; ++j)
          acc[i][j] = __builtin_amdgcn_mfma_f32_16x16x32_bf16(af[i], bfv[j], acc[i][j], 0, 0, 0);
    }
    __syncthreads();
  }

#pragma unroll
  for (int i = 0; i < 4; ++i) {
#pragma unroll
    for (int j = 0; j < 4; ++j) {
      int col = col0 + wn * 64 + j * 16 + lrow;
      float bv = HAS_BIAS ? bias[col] : 0.f;
#pragma unroll
      for (int r = 0; r < 4; ++r) {
        int row = row0 + wm * 64 + i * 16 + lgrp * 4 + r;
        float v = acc[i][j][r] + bv;
        if (ACC_IN) v += ((const float*)C)[(size_t)row * N + col];
        if (OUT_BF16) ((unsigned short*)C)[(size_t)row * N + col] = (unsigned short)f2bf(v);
        else          ((float*)C)[(size_t)row * N + col] = v;
      }
    }
  }
}

// ---------------- per-(t,h) scalars: dt, g, lambda ----------------
__global__ void scalar_kernel(const float* __restrict__ zx, const float* __restrict__ dtb,
    const float* __restrict__ alog, const float* __restrict__ Lm,
    float* __restrict__ dt, float* __restrict__ g_ht, float* __restrict__ lam) {
  int idx = blockIdx.x * 256 + threadIdx.x;
  if (idx >= T_LEN * NH) return;
  int t = idx >> 5, h = idx & 31;
  const float* row = zx + (size_t)t * PROJ_C;
  float dv = softplus_f(row[DIMC + CONVD + h] + dtb[h]);
  dt[t * NH + h] = dv;
  g_ht[h * T_LEN + t] = -expf(alog[h]) * dv;
#pragma unroll
  for (int l = 0; l < NLV; ++l)
    lam[((size_t)t * NH + h) * NLV + l] =
        softplus_f(Lm[h * NLV + l] * row[DIMC + CONVD + NH + h * NLV + l]);
}

// ---------------- per-head inclusive cumsum of g over t ----------------
__global__ __launch_bounds__(1024) void scan_kernel(const float* __restrict__ g_ht,
                                                    float* __restrict__ gc) {
  __shared__ float buf[1024];
  int h = blockIdx.x, t = threadIdx.x;
  buf[t] = g_ht[h * T_LEN + t];
  __syncthreads();
  for (int off = 1; off < 1024; off <<= 1) {
    float add = (t >= off) ? buf[t - off] : 0.f;
    __syncthreads();
    buf[t] += add;
    __syncthreads();
  }
  gc[h * T_LEN + t] = buf[t];
}

// ------- conv(K=4)+SiLU; writes x(f32), B/C hi/lo(bf16) -------
__global__ __launch_bounds__(256) void conv_kernel(const float* __restrict__ zx,
    const float* __restrict__ convw,
    float* __restrict__ xout,
    unsigned short* __restrict__ Bmh, unsigned short* __restrict__ Bml,
    unsigned short* __restrict__ Cmh, unsigned short* __restrict__ Cml) {
  const int c0 = blockIdx.x * 64, t0 = blockIdx.y * 64;
  const int cl = threadIdx.x & 63, q = threadIdx.x >> 6;
  const int c = c0 + cl;
  const float4 wv = *(const float4*)(convw + c * 4);
  const float warr[4] = {wv.x, wv.y, wv.z, wv.w};
#pragma unroll
  for (int it = 0; it < 16; ++it) {
    int tt = it * 4 + q;
    int t = t0 + tt;
    float acc = 0.f;
#pragma unroll
    for (int i = 0; i < 4; ++i) {
      int ts = t - 3 + i;
      if (ts >= 0) acc += zx[(size_t)ts * PROJ_C + DIMC + c] * warr[i];
    }
    float val = acc / (1.f + __expf(-acc));
    if (c < DIMC) {
      xout[(size_t)t * DIMC + c] = val;
    } else if (c < DIMC + DST) {
      short hi = f2bf(val);
      Bmh[t * DST + (c - DIMC)] = (unsigned short)hi;
      Bml[t * DST + (c - DIMC)] = (unsigned short)f2bf(val - bf2f(hi));
    } else {
      short hi = f2bf(val);
      Cmh[t * DST + (c - DIMC - DST)] = (unsigned short)hi;
      Cml[t * DST + (c - DIMC - DST)] = (unsigned short)f2bf(val - bf2f(hi));
    }
  }
}

// ------- attention, full f32 VALU (reference-faithful) -------
__global__ __launch_bounds__(256) void attn_f32(const float* __restrict__ qkf,
    const float* __restrict__ xf, const float* __restrict__ dt,
    const float* __restrict__ gc, const float* __restrict__ lam,
    const float* __restrict__ Dv, float* __restrict__ y) {
  __shared__ float v_lds[64][64];     // [s_local][p]
  __shared__ float qk_lds[64][65];    // [t_local][s_local], +1 pad
  __shared__ float lam_lds[64][17];   // [t_local][lvl]
  __shared__ float gcs[64];
  const int h = blockIdx.y;
  const int t0 = blockIdx.x * 64;
  const int tid = threadIdx.x;
  const int tl = tid & 63;
  const int pg = tid >> 6;
  const int t = t0 + tl;

  for (int i = tid; i < 64 * NLV; i += 256) {
    int r = i / NLV, l = i - r * NLV;
    lam_lds[r][l] = lam[((size_t)(t0 + r) * NH + h) * NLV + l];
  }
  const float gct = gc[h * T_LEN + t];
  const float Dh = Dv[h];
  float acc[16];
#pragma unroll
  for (int j = 0; j < 16; ++j) acc[j] = 0.f;

  for (int sb = 0; sb <= blockIdx.x; ++sb) {
    int s0 = sb * 64;
    __syncthreads();
#pragma unroll
    for (int i = 0; i < 4; ++i) {
      int e = i * 256 + tid;
      int ds = e >> 4, p4 = (e & 15) * 4;
      float dts = dt[(s0 + ds) * NH + h];
      float4 xv = *(const float4*)(xf + (size_t)(s0 + ds) * DIMC + h * 64 + p4);
      float4 vv = {xv.x * dts, xv.y * dts, xv.z * dts, xv.w * dts};
      *(float4*)&v_lds[ds][p4] = vv;
    }
#pragma unroll
    for (int i = 0; i < 4; ++i) {
      int e = i * 256 + tid;
      int tr = e >> 4, sc4 = (e & 15) * 4;
      float4 qv = *(const float4*)(qkf + (size_t)(t0 + tr) * T_LEN + s0 + sc4);
      qk_lds[tr][sc4 + 0] = qv.x;
      qk_lds[tr][sc4 + 1] = qv.y;
      qk_lds[tr][sc4 + 2] = qv.z;
      qk_lds[tr][sc4 + 3] = qv.w;
    }
    if (tid < 64) gcs[tid] = gc[h * T_LEN + s0 + tid];
    __syncthreads();

    for (int ds = 0; ds < 64; ++ds) {
      int s = s0 + ds;
      if (s > t) break;
      int lvl = (s == t) ? 0 : (32 - __clz(s ^ t));
      float w = qk_lds[tl][ds] * __expf(gct - gcs[ds]) * lam_lds[tl][lvl];
#pragma unroll
      for (int jj = 0; jj < 4; ++jj) {
        float4 vv = *(const float4*)&v_lds[ds][pg * 16 + jj * 4];
        acc[jj * 4 + 0] += w * vv.x;
        acc[jj * 4 + 1] += w * vv.y;
        acc[jj * 4 + 2] += w * vv.z;
        acc[jj * 4 + 3] += w * vv.w;
      }
    }
  }
  const size_t ybase = (size_t)t * DIMC + h * 64 + pg * 16;
#pragma unroll
  for (int jj = 0; jj < 4; ++jj) {
    float4 xv = *(const float4*)(xf + ybase + jj * 4);
    float4 ov = {acc[jj * 4 + 0] + Dh * xv.x, acc[jj * 4 + 1] + Dh * xv.y,
                 acc[jj * 4 + 2] + Dh * xv.z, acc[jj * 4 + 3] + Dh * xv.w};
    *(float4*)(y + ybase + jj * 4) = ov;
  }
}

// ------- gate (y * silu(z)) + RMSNorm -> bf16 hi/lo -------
__global__ __launch_bounds__(256) void gate_rms(const float* __restrict__ y,
    const float* __restrict__ zx, const float* __restrict__ nw,
    unsigned short* __restrict__ outh, unsigned short* __restrict__ outl) {
  const int t = blockIdx.x;
  const float* yr = y + (size_t)t * DIMC;
  const float* zr = zx + (size_t)t * PROJ_C;
  float vals[8];
  float ss = 0.f;
#pragma unroll
  for (int i = 0; i < 8; ++i) {
    int cidx = i * 256 + threadIdx.x;
    float z = zr[cidx];
    float yz = yr[cidx] * (z / (1.f + __expf(-z)));
    vals[i] = yz;
    ss += yz * yz;
  }
#pragma unroll
  for (int off = 32; off > 0; off >>= 1) ss += __shfl_xor(ss, off, 64);
  __shared__ float red[4];
  if ((threadIdx.x & 63) == 0) red[threadIdx.x >> 6] = ss;
  __syncthreads();
  float tot = red[0] + red[1] + red[2] + red[3];
  float rs = rsqrtf(tot * (1.f / DIMC) + 1e-5f);
#pragma unroll
  for (int i = 0; i < 8; ++i) {
    int cidx = i * 256 + threadIdx.x;
    float v = vals[i] * rs * nw[cidx];
    short hi = f2bf(v);
    outh[(size_t)t * DIMC + cidx] = (unsigned short)hi;
    outl[(size_t)t * DIMC + cidx] = (unsigned short)f2bf(v - bf2f(hi));
  }
}

extern "C" void kernel_launch(void* const* d_in, const int* in_sizes, int n_in,
                              void* d_out, int out_size, void* d_ws, size_t ws_size,
                              hipStream_t stream) {
  const float* hs   = (const float*)d_in[0];
  const float* w1   = (const float*)d_in[1];
  const float* b1   = (const float*)d_in[2];
  const float* cw   = (const float*)d_in[3];
  const float* dtb  = (const float*)d_in[4];
  const float* alog = (const float*)d_in[5];
  const float* Lm   = (const float*)d_in[6];
  const float* Dv   = (const float*)d_in[7];
  const float* nw   = (const float*)d_in[8];
  const float* w3   = (const float*)d_in[9];
  const float* b3   = (const float*)d_in[10];
  float* out = (float*)d_out;

  char* base = (char*)d_ws;
  size_t off = 0;
  auto alloc = [&](size_t b) {
    void* r = base + off;
    off = (off + b + 255) & ~(size_t)255;
    return r;
  };
  unsigned short* hs_h = (unsigned short*)alloc((size_t)T_LEN * HID * 2);
  unsigned short* hs_l = (unsigned short*)alloc((size_t)T_LEN * HID * 2);
  unsigned short* w1_h = (unsigned short*)alloc((size_t)PROJ_C * HID * 2);
  unsigned short* w1_l = (unsigned short*)alloc((size_t)PROJ_C * HID * 2);
  unsigned short* w3_h = (unsigned short*)alloc((size_t)HID * DIMC * 2);
  unsigned short* w3_l = (unsigned short*)alloc((size_t)HID * DIMC * 2);
  float* zx   = (float*)alloc((size_t)T_LEN * PROJ_C * 4);
  float* dt   = (float*)alloc((size_t)T_LEN * NH * 4);
  float* g_ht = (float*)alloc((size_t)NH * T_LEN * 4);
  float* gc   = (float*)alloc((size_t)NH * T_LEN * 4);
  float* lam  = (float*)alloc((size_t)T_LEN * NH * NLV * 4);
  float* xf   = (float*)alloc((size_t)T_LEN * DIMC * 4);
  unsigned short* Bmh = (unsigned short*)alloc((size_t)T_LEN * DST * 2);
  unsigned short* Bml = (unsigned short*)alloc((size_t)T_LEN * DST * 2);
  unsigned short* Cmh = (unsigned short*)alloc((size_t)T_LEN * DST * 2);
  unsigned short* Cml = (unsigned short*)alloc((size_t)T_LEN * DST * 2);
  float* qkf = (float*)alloc((size_t)T_LEN * T_LEN * 4);
  float* y = (float*)alloc((size_t)T_LEN * DIMC * 4);
  unsigned short* nbh = (unsigned short*)alloc((size_t)T_LEN * DIMC * 2);
  unsigned short* nbl = (unsigned short*)alloc((size_t)T_LEN * DIMC * 2);

  int n1 = T_LEN * HID;
  int n2 = PROJ_C * HID;
  int n3 = HID * DIMC;
  cast_split_kernel<<<(n1 / 4 + 255) / 256, 256, 0, stream>>>(hs, hs_h, hs_l, n1);
  cast_split_kernel<<<(n2 / 4 + 255) / 256, 256, 0, stream>>>(w1, w1_h, w1_l, n2);
  cast_split_kernel<<<(n3 / 4 + 255) / 256, 256, 0, stream>>>(w3, w3_h, w3_l, n3);

  // zx = hs*w1^T + b1, compensated (f32-equivalent)
  gemm_bt<0, 1, 0><<<dim3(PROJ_C / 128, T_LEN / 128), 256, 0, stream>>>(
      hs_h, w1_h, b1, zx, T_LEN, PROJ_C, HID);
  gemm_bt<0, 0, 1><<<dim3(PROJ_C / 128, T_LEN / 128), 256, 0, stream>>>(
      hs_h, w1_l, nullptr, zx, T_LEN, PROJ_C, HID);
  gemm_bt<0, 0, 1><<<dim3(PROJ_C / 128, T_LEN / 128), 256, 0, stream>>>(
      hs_l, w1_h, nullptr, zx, T_LEN, PROJ_C, HID);

  scalar_kernel<<<(T_LEN * NH) / 256, 256, 0, stream>>>(zx, dtb, alog, Lm, dt, g_ht, lam);
  scan_kernel<<<NH, 1024, 0, stream>>>(g_ht, gc);
  conv_kernel<<<dim3(CONVD / 64, T_LEN / 64), 256, 0, stream>>>(
      zx, cw, xf, Bmh, Bml, Cmh, Cml);

  // qk = C*B^T, compensated
  gemm_bt<0, 0, 0><<<dim3(T_LEN / 128, T_LEN / 128), 256, 0, stream>>>(
      Cmh, Bmh, nullptr, qkf, T_LEN, T_LEN, DST);
  gemm_bt<0, 0, 1><<<dim3(T_LEN / 128, T_LEN / 128), 256, 0, stream>>>(
      Cmh, Bml, nullptr, qkf, T_LEN, T_LEN, DST);
  gemm_bt<0, 0, 1><<<dim3(T_LEN / 128, T_LEN / 128), 256, 0, stream>>>(
      Cml, Bmh, nullptr, qkf, T_LEN, T_LEN, DST);

  attn_f32<<<dim3(T_LEN / 64, NH), 256, 0, stream>>>(qkf, xf, dt, gc, lam, Dv, y);
  gate_rms<<<T_LEN, 256, 0, stream>>>(y, zx, nw, nbh, nbl);

  // out = nb*w3^T + b3, compensated
  gemm_bt<0, 1, 0><<<dim3(HID / 128, T_LEN / 128), 256, 0, stream>>>(
      nbh, w3_h, b3, out, T_LEN, HID, DIMC);
  gemm_bt<0, 0, 1><<<dim3(HID / 128, T_LEN / 128), 256, 0, stream>>>(
      nbh, w3_l, nullptr, out, T_LEN, HID, DIMC);
  gemm_bt<0, 0, 1><<<dim3(HID / 128, T_LEN / 128), 256, 0, stream>>>(
      nbl, w3_h, nullptr, out, T_LEN, HID, DIMC);
}

// Round 8
// 318.237 us; speedup vs baseline: 1.9168x; 1.9168x over previous
//
#include <hip/hip_runtime.h>
#include <hip/hip_bf16.h>

#define T_LEN 1024
#define HID 1024
#define NH 32
#define HD 64
#define DIMC 2048
#define CONVD 2304
#define PROJ_C 4864
#define DST 128
#define NLV 15

typedef __attribute__((ext_vector_type(8))) short bf16x8;
typedef __attribute__((ext_vector_type(4))) float f32x4;

__device__ __forceinline__ float bf2f(short s) {
  unsigned u = ((unsigned)(unsigned short)s) << 16;
  return __builtin_bit_cast(float, u);
}
__device__ __forceinline__ short f2bf(float f) {
  return __builtin_bit_cast(short, __float2bfloat16(f));
}
__device__ __forceinline__ void gload16(const void* g, void* l) {
  __builtin_amdgcn_global_load_lds((const __attribute__((address_space(1))) unsigned int*)g,
                                   (__attribute__((address_space(3))) unsigned int*)l, 16, 0, 0);
}
__device__ __forceinline__ float softplus_f(float x) {
  return (x > 15.f) ? x : log1pf(expf(x));
}

// ---------------- split f32 -> bf16 hi + lo (Dekker) ----------------
__global__ void cast_split_kernel(const float* __restrict__ in,
    unsigned short* __restrict__ hi, unsigned short* __restrict__ lo, int n) {
  int i = (blockIdx.x * 256 + threadIdx.x) * 4;
  if (i >= n) return;
  float4 v = *(const float4*)(in + i);
  ushort4 h, l;
  h.x = (unsigned short)f2bf(v.x); l.x = (unsigned short)f2bf(v.x - bf2f((short)h.x));
  h.y = (unsigned short)f2bf(v.y); l.y = (unsigned short)f2bf(v.y - bf2f((short)h.y));
  h.z = (unsigned short)f2bf(v.z); l.z = (unsigned short)f2bf(v.z - bf2f((short)h.z));
  h.w = (unsigned short)f2bf(v.w); l.w = (unsigned short)f2bf(v.w - bf2f((short)h.w));
  *(ushort4*)(hi + i) = h;
  *(ushort4*)(lo + i) = l;
}

// ------- fused compensated bf16 GEMM: C[M,N] = (Ah+Al)*(Bh+Bl)^T + bias (f32 out) -------
// C = Al*Bh + Ah*Bl + Ah*Bh accumulated in one f32 chain (al*bl term ~2^-18, dropped)
template<int HAS_BIAS>
__global__ __launch_bounds__(256) void gemm_bt_comp(
    const unsigned short* __restrict__ Ah, const unsigned short* __restrict__ Al,
    const unsigned short* __restrict__ Bh, const unsigned short* __restrict__ Bl,
    const float* __restrict__ bias, float* __restrict__ C, int M, int N, int K) {
  __shared__ __align__(16) unsigned short Ash[128 * 64];
  __shared__ __align__(16) unsigned short Asl[128 * 64];
  __shared__ __align__(16) unsigned short Bsh[128 * 64];
  __shared__ __align__(16) unsigned short Bsl[128 * 64];
  const int tid = threadIdx.x;
  const int lane = tid & 63, wave = tid >> 6;
  const int wm = wave >> 1, wn = wave & 1;
  const int lrow = lane & 15, lgrp = lane >> 4;
  const int row0 = blockIdx.y * 128, col0 = blockIdx.x * 128;
  f32x4 zero4 = {0.f, 0.f, 0.f, 0.f};
  f32x4 acc[4][4];
  for (int i = 0; i < 4; ++i) for (int j = 0; j < 4; ++j) acc[i][j] = zero4;

  for (int k0 = 0; k0 < K; k0 += 64) {
#pragma unroll
    for (int it = 0; it < 4; ++it) {
      int e = (it * 256 + tid) * 8;
      int r = e >> 6, c = e & 63;
      gload16(Ah + (size_t)(row0 + r) * K + k0 + c, Ash + it * 2048 + wave * 512);
      gload16(Al + (size_t)(row0 + r) * K + k0 + c, Asl + it * 2048 + wave * 512);
      gload16(Bh + (size_t)(col0 + r) * K + k0 + c, Bsh + it * 2048 + wave * 512);
      gload16(Bl + (size_t)(col0 + r) * K + k0 + c, Bsl + it * 2048 + wave * 512);
    }
    __syncthreads();
#pragma unroll
    for (int kk = 0; kk < 2; ++kk) {
      bf16x8 afh[4], afl[4], bfh[4], bfl[4];
#pragma unroll
      for (int i = 0; i < 4; ++i) {
        int o = (wm * 64 + i * 16 + lrow) * 64 + kk * 32 + lgrp * 8;
        afh[i] = *(const bf16x8*)(Ash + o);
        afl[i] = *(const bf16x8*)(Asl + o);
      }
#pragma unroll
      for (int j = 0; j < 4; ++j) {
        int o = (wn * 64 + j * 16 + lrow) * 64 + kk * 32 + lgrp * 8;
        bfh[j] = *(const bf16x8*)(Bsh + o);
        bfl[j] = *(const bf16x8*)(Bsl + o);
      }
#pragma unroll
      for (int i = 0; i < 4; ++i)
#pragma unroll
        for (int j = 0; j < 4; ++j) {
          acc[i][j] = __builtin_amdgcn_mfma_f32_16x16x32_bf16(afl[i], bfh[j], acc[i][j], 0, 0, 0);
          acc[i][j] = __builtin_amdgcn_mfma_f32_16x16x32_bf16(afh[i], bfl[j], acc[i][j], 0, 0, 0);
          acc[i][j] = __builtin_amdgcn_mfma_f32_16x16x32_bf16(afh[i], bfh[j], acc[i][j], 0, 0, 0);
        }
    }
    __syncthreads();
  }

#pragma unroll
  for (int i = 0; i < 4; ++i) {
#pragma unroll
    for (int j = 0; j < 4; ++j) {
      int col = col0 + wn * 64 + j * 16 + lrow;
      float bv = HAS_BIAS ? bias[col] : 0.f;
#pragma unroll
      for (int r = 0; r < 4; ++r) {
        int row = row0 + wm * 64 + i * 16 + lgrp * 4 + r;
        C[(size_t)row * N + col] = acc[i][j][r] + bv;
      }
    }
  }
}

// ---------------- per-(t,h) scalars: dt, g, lambda ----------------
__global__ void scalar_kernel(const float* __restrict__ zx, const float* __restrict__ dtb,
    const float* __restrict__ alog, const float* __restrict__ Lm,
    float* __restrict__ dt, float* __restrict__ g_ht, float* __restrict__ lam) {
  int idx = blockIdx.x * 256 + threadIdx.x;
  if (idx >= T_LEN * NH) return;
  int t = idx >> 5, h = idx & 31;
  const float* row = zx + (size_t)t * PROJ_C;
  float dv = softplus_f(row[DIMC + CONVD + h] + dtb[h]);
  dt[t * NH + h] = dv;
  g_ht[h * T_LEN + t] = -expf(alog[h]) * dv;
#pragma unroll
  for (int l = 0; l < NLV; ++l)
    lam[((size_t)t * NH + h) * NLV + l] =
        softplus_f(Lm[h * NLV + l] * row[DIMC + CONVD + NH + h * NLV + l]);
}

// ---------------- per-head inclusive cumsum of g over t ----------------
__global__ __launch_bounds__(1024) void scan_kernel(const float* __restrict__ g_ht,
                                                    float* __restrict__ gc) {
  __shared__ float buf[1024];
  int h = blockIdx.x, t = threadIdx.x;
  buf[t] = g_ht[h * T_LEN + t];
  __syncthreads();
  for (int off = 1; off < 1024; off <<= 1) {
    float add = (t >= off) ? buf[t - off] : 0.f;
    __syncthreads();
    buf[t] += add;
    __syncthreads();
  }
  gc[h * T_LEN + t] = buf[t];
}

// ------- conv(K=4)+SiLU; writes x(f32), v^T hi/lo(bf16), B/C hi/lo -------
__global__ __launch_bounds__(256) void conv_kernel(const float* __restrict__ zx,
    const float* __restrict__ convw, const float* __restrict__ dt,
    float* __restrict__ xout,
    unsigned short* __restrict__ vth, unsigned short* __restrict__ vtl,
    unsigned short* __restrict__ Bmh, unsigned short* __restrict__ Bml,
    unsigned short* __restrict__ Cmh, unsigned short* __restrict__ Cml) {
  __shared__ float tile[64][65];
  const int c0 = blockIdx.x * 64, t0 = blockIdx.y * 64;
  const int cl = threadIdx.x & 63, q = threadIdx.x >> 6;
  const int c = c0 + cl;
  const float4 wv = *(const float4*)(convw + c * 4);
  const float warr[4] = {wv.x, wv.y, wv.z, wv.w};
#pragma unroll
  for (int it = 0; it < 16; ++it) {
    int tt = it * 4 + q;
    int t = t0 + tt;
    float acc = 0.f;
#pragma unroll
    for (int i = 0; i < 4; ++i) {
      int ts = t - 3 + i;
      if (ts >= 0) acc += zx[(size_t)ts * PROJ_C + DIMC + c] * warr[i];
    }
    float val = acc / (1.f + __expf(-acc));
    if (c < DIMC) {
      xout[(size_t)t * DIMC + c] = val;
      tile[tt][cl] = val;  // tile[time_local][chan_local]
    } else if (c < DIMC + DST) {
      short hi = f2bf(val);
      Bmh[t * DST + (c - DIMC)] = (unsigned short)hi;
      Bml[t * DST + (c - DIMC)] = (unsigned short)f2bf(val - bf2f(hi));
    } else {
      short hi = f2bf(val);
      Cmh[t * DST + (c - DIMC - DST)] = (unsigned short)hi;
      Cml[t * DST + (c - DIMC - DST)] = (unsigned short)f2bf(val - bf2f(hi));
    }
  }
  if (c0 < DIMC) {
    __syncthreads();
    const int tl = threadIdx.x & 63;
    const int t = t0 + tl;
#pragma unroll
    for (int it = 0; it < 16; ++it) {
      int cc = it * 4 + q;
      int c2 = c0 + cc;
      int h = c2 >> 6;
      float vv = tile[tl][cc] * dt[t * NH + h];  // v[t][c2], transpose-read (fixed)
      short hi = f2bf(vv);
      vth[(size_t)c2 * T_LEN + t] = (unsigned short)hi;
      vtl[(size_t)c2 * T_LEN + t] = (unsigned short)f2bf(vv - bf2f(hi));
    }
  }
}

// ------- attention MFMA, compensated: y = sum qk*decay*lam*v + D*x -------
__global__ __launch_bounds__(256) void attn_mfma(const float* __restrict__ qkf,
    const unsigned short* __restrict__ vth, const unsigned short* __restrict__ vtl,
    const float* __restrict__ gc, const float* __restrict__ lam,
    const float* __restrict__ xf, const float* __restrict__ Dv, float* __restrict__ y) {
  __shared__ __align__(16) unsigned short vth_lds[64 * 64];
  __shared__ __align__(16) unsigned short vtl_lds[64 * 64];
  __shared__ float gcs[64];
  __shared__ float lam_lds[64][17];
  const int h = blockIdx.y;
  const int ttile = gridDim.x - 1 - blockIdx.x;  // heavy blocks dispatched first
  const int t0 = ttile * 64;
  const int tid = threadIdx.x;
  const int lane = tid & 63, wave = tid >> 6;
  const int lrow = lane & 15, lgrp = lane >> 4;
  const int tglob = t0 + wave * 16 + lrow;

  for (int i = tid; i < 64 * NLV; i += 256) {
    int tl = i / NLV, l = i - tl * NLV;
    lam_lds[tl][l] = lam[((size_t)(t0 + tl) * NH + h) * NLV + l];
  }
  const float gct = gc[h * T_LEN + tglob];
  const float Dh = Dv[h];
  f32x4 zero4 = {0.f, 0.f, 0.f, 0.f};
  f32x4 acc[4];
  for (int j = 0; j < 4; ++j) acc[j] = zero4;

  const int nsb = ttile + 1;
  for (int sb = 0; sb < nsb; ++sb) {
    int s0 = sb * 64;
#pragma unroll
    for (int it = 0; it < 2; ++it) {
      int e = (it * 256 + tid) * 8;
      int p = e >> 6, ds = e & 63;
      gload16(vth + (size_t)(h * 64 + p) * T_LEN + s0 + ds, vth_lds + it * 2048 + wave * 512);
      gload16(vtl + (size_t)(h * 64 + p) * T_LEN + s0 + ds, vtl_lds + it * 2048 + wave * 512);
    }
    if (tid < 64) gcs[tid] = gc[h * T_LEN + s0 + tid];
    __syncthreads();
#pragma unroll
    for (int kk = 0; kk < 2; ++kk) {
      int sbase = s0 + kk * 32 + lgrp * 8;
      float4 q1 = *(const float4*)(qkf + (size_t)tglob * T_LEN + sbase);
      float4 q2 = *(const float4*)(qkf + (size_t)tglob * T_LEN + sbase + 4);
      float qv[8] = {q1.x, q1.y, q1.z, q1.w, q2.x, q2.y, q2.z, q2.w};
      bf16x8 ah, al;
#pragma unroll
      for (int e2 = 0; e2 < 8; ++e2) {
        int s = sbase + e2;
        float w = 0.f;
        if (s <= tglob) {
          float dec = __expf(gct - gcs[s - s0]);
          int lvl = (s == tglob) ? 0 : (32 - __clz(s ^ tglob));
          w = qv[e2] * dec * lam_lds[tglob - t0][lvl];
        }
        short hi = f2bf(w);
        ah[e2] = hi;
        al[e2] = f2bf(w - bf2f(hi));
      }
#pragma unroll
      for (int j = 0; j < 4; ++j) {
        int o = (j * 16 + lrow) * 64 + kk * 32 + lgrp * 8;
        bf16x8 bh = *(const bf16x8*)(vth_lds + o);
        bf16x8 bl = *(const bf16x8*)(vtl_lds + o);
        acc[j] = __builtin_amdgcn_mfma_f32_16x16x32_bf16(al, bh, acc[j], 0, 0, 0);
        acc[j] = __builtin_amdgcn_mfma_f32_16x16x32_bf16(ah, bl, acc[j], 0, 0, 0);
        acc[j] = __builtin_amdgcn_mfma_f32_16x16x32_bf16(ah, bh, acc[j], 0, 0, 0);
      }
    }
    __syncthreads();
  }
#pragma unroll
  for (int j = 0; j < 4; ++j) {
    int p = j * 16 + lrow;
    int cc = h * 64 + p;
#pragma unroll
    for (int r = 0; r < 4; ++r) {
      int t = t0 + wave * 16 + lgrp * 4 + r;
      y[(size_t)t * DIMC + cc] = acc[j][r] + xf[(size_t)t * DIMC + cc] * Dh;
    }
  }
}

// ------- gate (y * silu(z)) + RMSNorm -> bf16 hi/lo -------
__global__ __launch_bounds__(256) void gate_rms(const float* __restrict__ y,
    const float* __restrict__ zx, const float* __restrict__ nw,
    unsigned short* __restrict__ outh, unsigned short* __restrict__ outl) {
  const int t = blockIdx.x;
  const float* yr = y + (size_t)t * DIMC;
  const float* zr = zx + (size_t)t * PROJ_C;
  float vals[8];
  float ss = 0.f;
#pragma unroll
  for (int i = 0; i < 8; ++i) {
    int cidx = i * 256 + threadIdx.x;
    float z = zr[cidx];
    float yz = yr[cidx] * (z / (1.f + __expf(-z)));
    vals[i] = yz;
    ss += yz * yz;
  }
#pragma unroll
  for (int off = 32; off > 0; off >>= 1) ss += __shfl_xor(ss, off, 64);
  __shared__ float red[4];
  if ((threadIdx.x & 63) == 0) red[threadIdx.x >> 6] = ss;
  __syncthreads();
  float tot = red[0] + red[1] + red[2] + red[3];
  float rs = rsqrtf(tot * (1.f / DIMC) + 1e-5f);
#pragma unroll
  for (int i = 0; i < 8; ++i) {
    int cidx = i * 256 + threadIdx.x;
    float v = vals[i] * rs * nw[cidx];
    short hi = f2bf(v);
    outh[(size_t)t * DIMC + cidx] = (unsigned short)hi;
    outl[(size_t)t * DIMC + cidx] = (unsigned short)f2bf(v - bf2f(hi));
  }
}

extern "C" void kernel_launch(void* const* d_in, const int* in_sizes, int n_in,
                              void* d_out, int out_size, void* d_ws, size_t ws_size,
                              hipStream_t stream) {
  const float* hs   = (const float*)d_in[0];
  const float* w1   = (const float*)d_in[1];
  const float* b1   = (const float*)d_in[2];
  const float* cw   = (const float*)d_in[3];
  const float* dtb  = (const float*)d_in[4];
  const float* alog = (const float*)d_in[5];
  const float* Lm   = (const float*)d_in[6];
  const float* Dv   = (const float*)d_in[7];
  const float* nw   = (const float*)d_in[8];
  const float* w3   = (const float*)d_in[9];
  const float* b3   = (const float*)d_in[10];
  float* out = (float*)d_out;

  char* base = (char*)d_ws;
  size_t off = 0;
  auto alloc = [&](size_t b) {
    void* r = base + off;
    off = (off + b + 255) & ~(size_t)255;
    return r;
  };
  unsigned short* hs_h = (unsigned short*)alloc((size_t)T_LEN * HID * 2);
  unsigned short* hs_l = (unsigned short*)alloc((size_t)T_LEN * HID * 2);
  unsigned short* w1_h = (unsigned short*)alloc((size_t)PROJ_C * HID * 2);
  unsigned short* w1_l = (unsigned short*)alloc((size_t)PROJ_C * HID * 2);
  unsigned short* w3_h = (unsigned short*)alloc((size_t)HID * DIMC * 2);
  unsigned short* w3_l = (unsigned short*)alloc((size_t)HID * DIMC * 2);
  float* zx   = (float*)alloc((size_t)T_LEN * PROJ_C * 4);
  float* dt   = (float*)alloc((size_t)T_LEN * NH * 4);
  float* g_ht = (float*)alloc((size_t)NH * T_LEN * 4);
  float* gc   = (float*)alloc((size_t)NH * T_LEN * 4);
  float* lam  = (float*)alloc((size_t)T_LEN * NH * NLV * 4);
  float* xf   = (float*)alloc((size_t)T_LEN * DIMC * 4);
  unsigned short* vth = (unsigned short*)alloc((size_t)DIMC * T_LEN * 2);
  unsigned short* vtl = (unsigned short*)alloc((size_t)DIMC * T_LEN * 2);
  unsigned short* Bmh = (unsigned short*)alloc((size_t)T_LEN * DST * 2);
  unsigned short* Bml = (unsigned short*)alloc((size_t)T_LEN * DST * 2);
  unsigned short* Cmh = (unsigned short*)alloc((size_t)T_LEN * DST * 2);
  unsigned short* Cml = (unsigned short*)alloc((size_t)T_LEN * DST * 2);
  float* qkf = (float*)alloc((size_t)T_LEN * T_LEN * 4);
  float* y = (float*)alloc((size_t)T_LEN * DIMC * 4);
  unsigned short* nbh = (unsigned short*)alloc((size_t)T_LEN * DIMC * 2);
  unsigned short* nbl = (unsigned short*)alloc((size_t)T_LEN * DIMC * 2);

  int n1 = T_LEN * HID;
  int n2 = PROJ_C * HID;
  int n3 = HID * DIMC;
  cast_split_kernel<<<(n1 / 4 + 255) / 256, 256, 0, stream>>>(hs, hs_h, hs_l, n1);
  cast_split_kernel<<<(n2 / 4 + 255) / 256, 256, 0, stream>>>(w1, w1_h, w1_l, n2);
  cast_split_kernel<<<(n3 / 4 + 255) / 256, 256, 0, stream>>>(w3, w3_h, w3_l, n3);

  // zx = hs*w1^T + b1, fused compensated (f32-equivalent)
  gemm_bt_comp<1><<<dim3(PROJ_C / 128, T_LEN / 128), 256, 0, stream>>>(
      hs_h, hs_l, w1_h, w1_l, b1, zx, T_LEN, PROJ_C, HID);

  scalar_kernel<<<(T_LEN * NH) / 256, 256, 0, stream>>>(zx, dtb, alog, Lm, dt, g_ht, lam);
  scan_kernel<<<NH, 1024, 0, stream>>>(g_ht, gc);
  conv_kernel<<<dim3(CONVD / 64, T_LEN / 64), 256, 0, stream>>>(
      zx, cw, dt, xf, vth, vtl, Bmh, Bml, Cmh, Cml);

  // qk = C*B^T, fused compensated
  gemm_bt_comp<0><<<dim3(T_LEN / 128, T_LEN / 128), 256, 0, stream>>>(
      Cmh, Cml, Bmh, Bml, nullptr, qkf, T_LEN, T_LEN, DST);

  attn_mfma<<<dim3(T_LEN / 64, NH), 256, 0, stream>>>(qkf, vth, vtl, gc, lam, xf, Dv, y);
  gate_rms<<<T_LEN, 256, 0, stream>>>(y, zx, nw, nbh, nbl);

  // out = nb*w3^T + b3, fused compensated
  gemm_bt_comp<1><<<dim3(HID / 128, T_LEN / 128), 256, 0, stream>>>(
      nbh, nbl, w3_h, w3_l, b3, out, T_LEN, HID, DIMC);
}

// Round 9
// 279.350 us; speedup vs baseline: 2.1836x; 1.1392x over previous
//
#include <hip/hip_runtime.h>
#include <hip/hip_bf16.h>

#define T_LEN 1024
#define HID 1024
#define NH 32
#define HD 64
#define DIMC 2048
#define CONVD 2304
#define PROJ_C 4864
#define DST 128
#define NLV 15

typedef __attribute__((ext_vector_type(8))) short bf16x8;
typedef __attribute__((ext_vector_type(4))) float f32x4;

__device__ __forceinline__ float bf2f(short s) {
  unsigned u = ((unsigned)(unsigned short)s) << 16;
  return __builtin_bit_cast(float, u);
}
__device__ __forceinline__ short f2bf(float f) {
  return __builtin_bit_cast(short, __float2bfloat16(f));
}
__device__ __forceinline__ void gload16(const void* g, void* l) {
  __builtin_amdgcn_global_load_lds((const __attribute__((address_space(1))) unsigned int*)g,
                                   (__attribute__((address_space(3))) unsigned int*)l, 16, 0, 0);
}
__device__ __forceinline__ float softplus_f(float x) {
  return (x > 15.f) ? x : log1pf(expf(x));
}

// ---------------- split f32 -> bf16 hi + lo (Dekker) ----------------
__global__ void cast_split_kernel(const float* __restrict__ in,
    unsigned short* __restrict__ hi, unsigned short* __restrict__ lo, int n) {
  int i = (blockIdx.x * 256 + threadIdx.x) * 4;
  if (i >= n) return;
  float4 v = *(const float4*)(in + i);
  ushort4 h, l;
  h.x = (unsigned short)f2bf(v.x); l.x = (unsigned short)f2bf(v.x - bf2f((short)h.x));
  h.y = (unsigned short)f2bf(v.y); l.y = (unsigned short)f2bf(v.y - bf2f((short)h.y));
  h.z = (unsigned short)f2bf(v.z); l.z = (unsigned short)f2bf(v.z - bf2f((short)h.z));
  h.w = (unsigned short)f2bf(v.w); l.w = (unsigned short)f2bf(v.w - bf2f((short)h.w));
  *(ushort4*)(hi + i) = h;
  *(ushort4*)(lo + i) = l;
}

// ------- 64x64-tile fused compensated bf16 GEMM (high block count) -------
// C[M,N] = (Ah+Al)*(Bh+Bl)^T (+bias); ATOMIC: split-K over grid.z, atomicAdd into C
template<int HAS_BIAS, int ATOMIC>
__global__ __launch_bounds__(256) void gemm64_comp(
    const unsigned short* __restrict__ Ah, const unsigned short* __restrict__ Al,
    const unsigned short* __restrict__ Bh, const unsigned short* __restrict__ Bl,
    const float* __restrict__ bias, float* __restrict__ C, int M, int N, int K) {
  __shared__ __align__(16) unsigned short Ash[64 * 64];
  __shared__ __align__(16) unsigned short Asl[64 * 64];
  __shared__ __align__(16) unsigned short Bsh[64 * 64];
  __shared__ __align__(16) unsigned short Bsl[64 * 64];
  const int tid = threadIdx.x;
  const int lane = tid & 63, wave = tid >> 6;
  const int wm = wave >> 1, wn = wave & 1;
  const int lrow = lane & 15, lgrp = lane >> 4;
  const int row0 = blockIdx.y * 64, col0 = blockIdx.x * 64;
  int k0beg = 0, k0end = K;
  if (ATOMIC) {
    int kc = K / gridDim.z;
    k0beg = blockIdx.z * kc;
    k0end = k0beg + kc;
  }
  f32x4 zero4 = {0.f, 0.f, 0.f, 0.f};
  f32x4 acc[2][2];
  for (int i = 0; i < 2; ++i) for (int j = 0; j < 2; ++j) acc[i][j] = zero4;

  for (int k0 = k0beg; k0 < k0end; k0 += 64) {
#pragma unroll
    for (int it = 0; it < 2; ++it) {
      int e = (it * 256 + tid) * 8;
      int r = e >> 6, c = e & 63;
      gload16(Ah + (size_t)(row0 + r) * K + k0 + c, Ash + it * 2048 + wave * 512);
      gload16(Al + (size_t)(row0 + r) * K + k0 + c, Asl + it * 2048 + wave * 512);
      gload16(Bh + (size_t)(col0 + r) * K + k0 + c, Bsh + it * 2048 + wave * 512);
      gload16(Bl + (size_t)(col0 + r) * K + k0 + c, Bsl + it * 2048 + wave * 512);
    }
    __syncthreads();
#pragma unroll
    for (int kk = 0; kk < 2; ++kk) {
      bf16x8 afh[2], afl[2], bfh[2], bfl[2];
#pragma unroll
      for (int i = 0; i < 2; ++i) {
        int o = (wm * 32 + i * 16 + lrow) * 64 + kk * 32 + lgrp * 8;
        afh[i] = *(const bf16x8*)(Ash + o);
        afl[i] = *(const bf16x8*)(Asl + o);
      }
#pragma unroll
      for (int j = 0; j < 2; ++j) {
        int o = (wn * 32 + j * 16 + lrow) * 64 + kk * 32 + lgrp * 8;
        bfh[j] = *(const bf16x8*)(Bsh + o);
        bfl[j] = *(const bf16x8*)(Bsl + o);
      }
#pragma unroll
      for (int i = 0; i < 2; ++i)
#pragma unroll
        for (int j = 0; j < 2; ++j) {
          acc[i][j] = __builtin_amdgcn_mfma_f32_16x16x32_bf16(afl[i], bfh[j], acc[i][j], 0, 0, 0);
          acc[i][j] = __builtin_amdgcn_mfma_f32_16x16x32_bf16(afh[i], bfl[j], acc[i][j], 0, 0, 0);
          acc[i][j] = __builtin_amdgcn_mfma_f32_16x16x32_bf16(afh[i], bfh[j], acc[i][j], 0, 0, 0);
        }
    }
    __syncthreads();
  }

#pragma unroll
  for (int i = 0; i < 2; ++i) {
#pragma unroll
    for (int j = 0; j < 2; ++j) {
      int col = col0 + wn * 32 + j * 16 + lrow;
      float bv = (HAS_BIAS && (!ATOMIC || blockIdx.z == 0)) ? bias[col] : 0.f;
#pragma unroll
      for (int r = 0; r < 2 * 2; ++r) {
        int row = row0 + wm * 32 + i * 16 + lgrp * 4 + r;
        float v = acc[i][j][r] + bv;
        if (ATOMIC) atomicAdd(&C[(size_t)row * N + col], v);
        else        C[(size_t)row * N + col] = v;
      }
    }
  }
}

// ---------------- per-(t,h) scalars: dt, g, lambda ----------------
__global__ void scalar_kernel(const float* __restrict__ zx, const float* __restrict__ dtb,
    const float* __restrict__ alog, const float* __restrict__ Lm,
    float* __restrict__ dt, float* __restrict__ g_ht, float* __restrict__ lam) {
  int idx = blockIdx.x * 256 + threadIdx.x;
  if (idx >= T_LEN * NH) return;
  int t = idx >> 5, h = idx & 31;
  const float* row = zx + (size_t)t * PROJ_C;
  float dv = softplus_f(row[DIMC + CONVD + h] + dtb[h]);
  dt[t * NH + h] = dv;
  g_ht[h * T_LEN + t] = -expf(alog[h]) * dv;
#pragma unroll
  for (int l = 0; l < NLV; ++l)
    lam[((size_t)t * NH + h) * NLV + l] =
        softplus_f(Lm[h * NLV + l] * row[DIMC + CONVD + NH + h * NLV + l]);
}

// ---------------- per-head inclusive cumsum of g over t ----------------
__global__ __launch_bounds__(1024) void scan_kernel(const float* __restrict__ g_ht,
                                                    float* __restrict__ gc) {
  __shared__ float buf[1024];
  int h = blockIdx.x, t = threadIdx.x;
  buf[t] = g_ht[h * T_LEN + t];
  __syncthreads();
  for (int off = 1; off < 1024; off <<= 1) {
    float add = (t >= off) ? buf[t - off] : 0.f;
    __syncthreads();
    buf[t] += add;
    __syncthreads();
  }
  gc[h * T_LEN + t] = buf[t];
}

// ------- conv(K=4)+SiLU; writes x(f32), v^T hi/lo(bf16), B/C hi/lo -------
__global__ __launch_bounds__(256) void conv_kernel(const float* __restrict__ zx,
    const float* __restrict__ convw, const float* __restrict__ dt,
    float* __restrict__ xout,
    unsigned short* __restrict__ vth, unsigned short* __restrict__ vtl,
    unsigned short* __restrict__ Bmh, unsigned short* __restrict__ Bml,
    unsigned short* __restrict__ Cmh, unsigned short* __restrict__ Cml) {
  __shared__ float tile[64][65];
  const int c0 = blockIdx.x * 64, t0 = blockIdx.y * 64;
  const int cl = threadIdx.x & 63, q = threadIdx.x >> 6;
  const int c = c0 + cl;
  const float4 wv = *(const float4*)(convw + c * 4);
  const float warr[4] = {wv.x, wv.y, wv.z, wv.w};
#pragma unroll
  for (int it = 0; it < 16; ++it) {
    int tt = it * 4 + q;
    int t = t0 + tt;
    float acc = 0.f;
#pragma unroll
    for (int i = 0; i < 4; ++i) {
      int ts = t - 3 + i;
      if (ts >= 0) acc += zx[(size_t)ts * PROJ_C + DIMC + c] * warr[i];
    }
    float val = acc / (1.f + __expf(-acc));
    if (c < DIMC) {
      xout[(size_t)t * DIMC + c] = val;
      tile[tt][cl] = val;  // tile[time_local][chan_local]
    } else if (c < DIMC + DST) {
      short hi = f2bf(val);
      Bmh[t * DST + (c - DIMC)] = (unsigned short)hi;
      Bml[t * DST + (c - DIMC)] = (unsigned short)f2bf(val - bf2f(hi));
    } else {
      short hi = f2bf(val);
      Cmh[t * DST + (c - DIMC - DST)] = (unsigned short)hi;
      Cml[t * DST + (c - DIMC - DST)] = (unsigned short)f2bf(val - bf2f(hi));
    }
  }
  if (c0 < DIMC) {
    __syncthreads();
    const int tl = threadIdx.x & 63;
    const int t = t0 + tl;
#pragma unroll
    for (int it = 0; it < 16; ++it) {
      int cc = it * 4 + q;
      int c2 = c0 + cc;
      int h = c2 >> 6;
      float vv = tile[tl][cc] * dt[t * NH + h];  // v[t][c2], transpose-read
      short hi = f2bf(vv);
      vth[(size_t)c2 * T_LEN + t] = (unsigned short)hi;
      vtl[(size_t)c2 * T_LEN + t] = (unsigned short)f2bf(vv - bf2f(hi));
    }
  }
}

// ------- attention MFMA, compensated: y = sum qk*decay*lam*v + D*x -------
__global__ __launch_bounds__(256) void attn_mfma(const float* __restrict__ qkf,
    const unsigned short* __restrict__ vth, const unsigned short* __restrict__ vtl,
    const float* __restrict__ gc, const float* __restrict__ lam,
    const float* __restrict__ xf, const float* __restrict__ Dv, float* __restrict__ y) {
  __shared__ __align__(16) unsigned short vth_lds[64 * 64];
  __shared__ __align__(16) unsigned short vtl_lds[64 * 64];
  __shared__ float gcs[64];
  __shared__ float lam_lds[64][17];
  const int h = blockIdx.y;
  const int ttile = gridDim.x - 1 - blockIdx.x;  // heavy blocks dispatched first
  const int t0 = ttile * 64;
  const int tid = threadIdx.x;
  const int lane = tid & 63, wave = tid >> 6;
  const int lrow = lane & 15, lgrp = lane >> 4;
  const int tglob = t0 + wave * 16 + lrow;

  for (int i = tid; i < 64 * NLV; i += 256) {
    int tl = i / NLV, l = i - tl * NLV;
    lam_lds[tl][l] = lam[((size_t)(t0 + tl) * NH + h) * NLV + l];
  }
  const float gct = gc[h * T_LEN + tglob];
  const float Dh = Dv[h];
  f32x4 zero4 = {0.f, 0.f, 0.f, 0.f};
  f32x4 acc[4];
  for (int j = 0; j < 4; ++j) acc[j] = zero4;

  const int nsb = ttile + 1;
  for (int sb = 0; sb < nsb; ++sb) {
    int s0 = sb * 64;
#pragma unroll
    for (int it = 0; it < 2; ++it) {
      int e = (it * 256 + tid) * 8;
      int p = e >> 6, ds = e & 63;
      gload16(vth + (size_t)(h * 64 + p) * T_LEN + s0 + ds, vth_lds + it * 2048 + wave * 512);
      gload16(vtl + (size_t)(h * 64 + p) * T_LEN + s0 + ds, vtl_lds + it * 2048 + wave * 512);
    }
    if (tid < 64) gcs[tid] = gc[h * T_LEN + s0 + tid];
    __syncthreads();
#pragma unroll
    for (int kk = 0; kk < 2; ++kk) {
      int sbase = s0 + kk * 32 + lgrp * 8;
      float4 q1 = *(const float4*)(qkf + (size_t)tglob * T_LEN + sbase);
      float4 q2 = *(const float4*)(qkf + (size_t)tglob * T_LEN + sbase + 4);
      float qv[8] = {q1.x, q1.y, q1.z, q1.w, q2.x, q2.y, q2.z, q2.w};
      bf16x8 ah, al;
#pragma unroll
      for (int e2 = 0; e2 < 8; ++e2) {
        int s = sbase + e2;
        float w = 0.f;
        if (s <= tglob) {
          float dec = __expf(gct - gcs[s - s0]);
          int lvl = (s == tglob) ? 0 : (32 - __clz(s ^ tglob));
          w = qv[e2] * dec * lam_lds[tglob - t0][lvl];
        }
        short hi = f2bf(w);
        ah[e2] = hi;
        al[e2] = f2bf(w - bf2f(hi));
      }
#pragma unroll
      for (int j = 0; j < 4; ++j) {
        int o = (j * 16 + lrow) * 64 + kk * 32 + lgrp * 8;
        bf16x8 bh = *(const bf16x8*)(vth_lds + o);
        bf16x8 bl = *(const bf16x8*)(vtl_lds + o);
        acc[j] = __builtin_amdgcn_mfma_f32_16x16x32_bf16(al, bh, acc[j], 0, 0, 0);
        acc[j] = __builtin_amdgcn_mfma_f32_16x16x32_bf16(ah, bl, acc[j], 0, 0, 0);
        acc[j] = __builtin_amdgcn_mfma_f32_16x16x32_bf16(ah, bh, acc[j], 0, 0, 0);
      }
    }
    __syncthreads();
  }
#pragma unroll
  for (int j = 0; j < 4; ++j) {
    int p = j * 16 + lrow;
    int cc = h * 64 + p;
#pragma unroll
    for (int r = 0; r < 4; ++r) {
      int t = t0 + wave * 16 + lgrp * 4 + r;
      y[(size_t)t * DIMC + cc] = acc[j][r] + xf[(size_t)t * DIMC + cc] * Dh;
    }
  }
}

// ------- gate (y * silu(z)) + RMSNorm -> bf16 hi/lo -------
__global__ __launch_bounds__(256) void gate_rms(const float* __restrict__ y,
    const float* __restrict__ zx, const float* __restrict__ nw,
    unsigned short* __restrict__ outh, unsigned short* __restrict__ outl) {
  const int t = blockIdx.x;
  const float* yr = y + (size_t)t * DIMC;
  const float* zr = zx + (size_t)t * PROJ_C;
  float vals[8];
  float ss = 0.f;
#pragma unroll
  for (int i = 0; i < 8; ++i) {
    int cidx = i * 256 + threadIdx.x;
    float z = zr[cidx];
    float yz = yr[cidx] * (z / (1.f + __expf(-z)));
    vals[i] = yz;
    ss += yz * yz;
  }
#pragma unroll
  for (int off = 32; off > 0; off >>= 1) ss += __shfl_xor(ss, off, 64);
  __shared__ float red[4];
  if ((threadIdx.x & 63) == 0) red[threadIdx.x >> 6] = ss;
  __syncthreads();
  float tot = red[0] + red[1] + red[2] + red[3];
  float rs = rsqrtf(tot * (1.f / DIMC) + 1e-5f);
#pragma unroll
  for (int i = 0; i < 8; ++i) {
    int cidx = i * 256 + threadIdx.x;
    float v = vals[i] * rs * nw[cidx];
    short hi = f2bf(v);
    outh[(size_t)t * DIMC + cidx] = (unsigned short)hi;
    outl[(size_t)t * DIMC + cidx] = (unsigned short)f2bf(v - bf2f(hi));
  }
}

extern "C" void kernel_launch(void* const* d_in, const int* in_sizes, int n_in,
                              void* d_out, int out_size, void* d_ws, size_t ws_size,
                              hipStream_t stream) {
  const float* hs   = (const float*)d_in[0];
  const float* w1   = (const float*)d_in[1];
  const float* b1   = (const float*)d_in[2];
  const float* cw   = (const float*)d_in[3];
  const float* dtb  = (const float*)d_in[4];
  const float* alog = (const float*)d_in[5];
  const float* Lm   = (const float*)d_in[6];
  const float* Dv   = (const float*)d_in[7];
  const float* nw   = (const float*)d_in[8];
  const float* w3   = (const float*)d_in[9];
  const float* b3   = (const float*)d_in[10];
  float* out = (float*)d_out;

  char* base = (char*)d_ws;
  size_t off = 0;
  auto alloc = [&](size_t b) {
    void* r = base + off;
    off = (off + b + 255) & ~(size_t)255;
    return r;
  };
  unsigned short* hs_h = (unsigned short*)alloc((size_t)T_LEN * HID * 2);
  unsigned short* hs_l = (unsigned short*)alloc((size_t)T_LEN * HID * 2);
  unsigned short* w1_h = (unsigned short*)alloc((size_t)PROJ_C * HID * 2);
  unsigned short* w1_l = (unsigned short*)alloc((size_t)PROJ_C * HID * 2);
  unsigned short* w3_h = (unsigned short*)alloc((size_t)HID * DIMC * 2);
  unsigned short* w3_l = (unsigned short*)alloc((size_t)HID * DIMC * 2);
  float* zx   = (float*)alloc((size_t)T_LEN * PROJ_C * 4);
  float* dt   = (float*)alloc((size_t)T_LEN * NH * 4);
  float* g_ht = (float*)alloc((size_t)NH * T_LEN * 4);
  float* gc   = (float*)alloc((size_t)NH * T_LEN * 4);
  float* lam  = (float*)alloc((size_t)T_LEN * NH * NLV * 4);
  float* xf   = (float*)alloc((size_t)T_LEN * DIMC * 4);
  unsigned short* vth = (unsigned short*)alloc((size_t)DIMC * T_LEN * 2);
  unsigned short* vtl = (unsigned short*)alloc((size_t)DIMC * T_LEN * 2);
  unsigned short* Bmh = (unsigned short*)alloc((size_t)T_LEN * DST * 2);
  unsigned short* Bml = (unsigned short*)alloc((size_t)T_LEN * DST * 2);
  unsigned short* Cmh = (unsigned short*)alloc((size_t)T_LEN * DST * 2);
  unsigned short* Cml = (unsigned short*)alloc((size_t)T_LEN * DST * 2);
  float* qkf = (float*)alloc((size_t)T_LEN * T_LEN * 4);
  float* y = (float*)alloc((size_t)T_LEN * DIMC * 4);
  unsigned short* nbh = (unsigned short*)alloc((size_t)T_LEN * DIMC * 2);
  unsigned short* nbl = (unsigned short*)alloc((size_t)T_LEN * DIMC * 2);

  int n1 = T_LEN * HID;
  int n2 = PROJ_C * HID;
  int n3 = HID * DIMC;
  cast_split_kernel<<<(n1 / 4 + 255) / 256, 256, 0, stream>>>(hs, hs_h, hs_l, n1);
  cast_split_kernel<<<(n2 / 4 + 255) / 256, 256, 0, stream>>>(w1, w1_h, w1_l, n2);
  cast_split_kernel<<<(n3 / 4 + 255) / 256, 256, 0, stream>>>(w3, w3_h, w3_l, n3);

  // zx = hs*w1^T + b1 (f32-equivalent), 76x16 = 1216 blocks
  gemm64_comp<1, 0><<<dim3(PROJ_C / 64, T_LEN / 64), 256, 0, stream>>>(
      hs_h, hs_l, w1_h, w1_l, b1, zx, T_LEN, PROJ_C, HID);

  scalar_kernel<<<(T_LEN * NH) / 256, 256, 0, stream>>>(zx, dtb, alog, Lm, dt, g_ht, lam);
  scan_kernel<<<NH, 1024, 0, stream>>>(g_ht, gc);
  conv_kernel<<<dim3(CONVD / 64, T_LEN / 64), 256, 0, stream>>>(
      zx, cw, dt, xf, vth, vtl, Bmh, Bml, Cmh, Cml);

  // qk = C*B^T, 16x16 = 256 blocks
  gemm64_comp<0, 0><<<dim3(T_LEN / 64, T_LEN / 64), 256, 0, stream>>>(
      Cmh, Cml, Bmh, Bml, nullptr, qkf, T_LEN, T_LEN, DST);

  attn_mfma<<<dim3(T_LEN / 64, NH), 256, 0, stream>>>(qkf, vth, vtl, gc, lam, xf, Dv, y);
  gate_rms<<<T_LEN, 256, 0, stream>>>(y, zx, nw, nbh, nbl);

  // out = nb*w3^T + b3: split-K x4 -> 16x16x4 = 1024 blocks, atomicAdd into zeroed out
  hipMemsetAsync(out, 0, (size_t)out_size * 4, stream);
  gemm64_comp<1, 1><<<dim3(HID / 64, T_LEN / 64, 4), 256, 0, stream>>>(
      nbh, nbl, w3_h, w3_l, b3, out, T_LEN, HID, DIMC);
}

// Round 11
// 268.040 us; speedup vs baseline: 2.2758x; 1.0422x over previous
//
#include <hip/hip_runtime.h>
#include <hip/hip_bf16.h>

#define T_LEN 1024
#define HID 1024
#define NH 32
#define HD 64
#define DIMC 2048
#define CONVD 2304
#define PROJ_C 4864
#define DST 128
#define NLV 15

typedef __attribute__((ext_vector_type(8))) short bf16x8;
typedef __attribute__((ext_vector_type(4))) float f32x4;

__device__ __forceinline__ float bf2f(short s) {
  unsigned u = ((unsigned)(unsigned short)s) << 16;
  return __builtin_bit_cast(float, u);
}
__device__ __forceinline__ short f2bf(float f) {
  return __builtin_bit_cast(short, __float2bfloat16(f));
}
__device__ __forceinline__ void gload16(const void* g, void* l) {
  __builtin_amdgcn_global_load_lds((const __attribute__((address_space(1))) unsigned int*)g,
                                   (__attribute__((address_space(3))) unsigned int*)l, 16, 0, 0);
}
__device__ __forceinline__ float softplus_f(float x) {
  return (x > 15.f) ? x : log1pf(expf(x));
}

// ---------------- split f32 -> bf16 hi + lo (Dekker) ----------------
__global__ void cast_split_kernel(const float* __restrict__ in,
    unsigned short* __restrict__ hi, unsigned short* __restrict__ lo, int n) {
  int i = (blockIdx.x * 256 + threadIdx.x) * 4;
  if (i >= n) return;
  float4 v = *(const float4*)(in + i);
  ushort4 h, l;
  h.x = (unsigned short)f2bf(v.x); l.x = (unsigned short)f2bf(v.x - bf2f((short)h.x));
  h.y = (unsigned short)f2bf(v.y); l.y = (unsigned short)f2bf(v.y - bf2f((short)h.y));
  h.z = (unsigned short)f2bf(v.z); l.z = (unsigned short)f2bf(v.z - bf2f((short)h.z));
  h.w = (unsigned short)f2bf(v.w); l.w = (unsigned short)f2bf(v.w - bf2f((short)h.w));
  *(ushort4*)(hi + i) = h;
  *(ushort4*)(lo + i) = l;
}

// ------- 64x64-tile fused compensated bf16 GEMM, LDS XOR-swizzled -------
// LDS tile [64 rows][8 blocks of 16B]; physical block = logical ^ (row&7).
// global_load_lds writes linearly, so the SOURCE col is pre-swizzled and the
// ds_read offset applies the same XOR (both-sides rule).
template<int HAS_BIAS, int ATOMIC>
__global__ __launch_bounds__(256) void gemm64_comp(
    const unsigned short* __restrict__ Ah, const unsigned short* __restrict__ Al,
    const unsigned short* __restrict__ Bh, const unsigned short* __restrict__ Bl,
    const float* __restrict__ bias, float* __restrict__ C, int M, int N, int K) {
  __shared__ __align__(16) unsigned short Ash[64 * 64];
  __shared__ __align__(16) unsigned short Asl[64 * 64];
  __shared__ __align__(16) unsigned short Bsh[64 * 64];
  __shared__ __align__(16) unsigned short Bsl[64 * 64];
  const int tid = threadIdx.x;
  const int lane = tid & 63, wave = tid >> 6;
  const int wm = wave >> 1, wn = wave & 1;
  const int lrow = lane & 15, lgrp = lane >> 4;
  const int row0 = blockIdx.y * 64, col0 = blockIdx.x * 64;
  int k0beg = 0, k0end = K;
  if (ATOMIC) {
    int kc = K / gridDim.z;
    k0beg = blockIdx.z * kc;
    k0end = k0beg + kc;
  }
  f32x4 zero4 = {0.f, 0.f, 0.f, 0.f};
  f32x4 acc[2][2];
  for (int i = 0; i < 2; ++i) for (int j = 0; j < 2; ++j) acc[i][j] = zero4;

  for (int k0 = k0beg; k0 < k0end; k0 += 64) {
#pragma unroll
    for (int it = 0; it < 2; ++it) {
      int idx = it * 256 + tid;      // staged 16B-block index = r*8 + cb
      int r = idx >> 3, cb = idx & 7;
      int c = (cb ^ (r & 7)) * 8;    // pre-swizzled source col
      gload16(Ah + (size_t)(row0 + r) * K + k0 + c, Ash + it * 2048 + wave * 512);
      gload16(Al + (size_t)(row0 + r) * K + k0 + c, Asl + it * 2048 + wave * 512);
      gload16(Bh + (size_t)(col0 + r) * K + k0 + c, Bsh + it * 2048 + wave * 512);
      gload16(Bl + (size_t)(col0 + r) * K + k0 + c, Bsl + it * 2048 + wave * 512);
    }
    __syncthreads();
#pragma unroll
    for (int kk = 0; kk < 2; ++kk) {
      bf16x8 afh[2], afl[2], bfh[2], bfl[2];
#pragma unroll
      for (int i = 0; i < 2; ++i) {
        int row = wm * 32 + i * 16 + lrow;
        int o = row * 64 + (((kk * 4 + lgrp) ^ (row & 7)) * 8);
        afh[i] = *(const bf16x8*)(Ash + o);
        afl[i] = *(const bf16x8*)(Asl + o);
      }
#pragma unroll
      for (int j = 0; j < 2; ++j) {
        int row = wn * 32 + j * 16 + lrow;
        int o = row * 64 + (((kk * 4 + lgrp) ^ (row & 7)) * 8);
        bfh[j] = *(const bf16x8*)(Bsh + o);
        bfl[j] = *(const bf16x8*)(Bsl + o);
      }
#pragma unroll
      for (int i = 0; i < 2; ++i)
#pragma unroll
        for (int j = 0; j < 2; ++j) {
          acc[i][j] = __builtin_amdgcn_mfma_f32_16x16x32_bf16(afl[i], bfh[j], acc[i][j], 0, 0, 0);
          acc[i][j] = __builtin_amdgcn_mfma_f32_16x16x32_bf16(afh[i], bfl[j], acc[i][j], 0, 0, 0);
          acc[i][j] = __builtin_amdgcn_mfma_f32_16x16x32_bf16(afh[i], bfh[j], acc[i][j], 0, 0, 0);
        }
    }
    __syncthreads();
  }

#pragma unroll
  for (int i = 0; i < 2; ++i) {
#pragma unroll
    for (int j = 0; j < 2; ++j) {
      int col = col0 + wn * 32 + j * 16 + lrow;
      float bv = (HAS_BIAS && (!ATOMIC || blockIdx.z == 0)) ? bias[col] : 0.f;
#pragma unroll
      for (int r = 0; r < 2 * 2; ++r) {
        int row = row0 + wm * 32 + i * 16 + lgrp * 4 + r;
        float v = acc[i][j][r] + bv;
        if (ATOMIC) atomicAdd(&C[(size_t)row * N + col], v);
        else        C[(size_t)row * N + col] = v;
      }
    }
  }
}

// ---------------- per-(t,h) scalars: dt, g, lambda ----------------
__global__ void scalar_kernel(const float* __restrict__ zx, const float* __restrict__ dtb,
    const float* __restrict__ alog, const float* __restrict__ Lm,
    float* __restrict__ dt, float* __restrict__ g_ht, float* __restrict__ lam) {
  int idx = blockIdx.x * 256 + threadIdx.x;
  if (idx >= T_LEN * NH) return;
  int t = idx >> 5, h = idx & 31;
  const float* row = zx + (size_t)t * PROJ_C;
  float dv = softplus_f(row[DIMC + CONVD + h] + dtb[h]);
  dt[t * NH + h] = dv;
  g_ht[h * T_LEN + t] = -expf(alog[h]) * dv;
#pragma unroll
  for (int l = 0; l < NLV; ++l)
    lam[((size_t)t * NH + h) * NLV + l] =
        softplus_f(Lm[h * NLV + l] * row[DIMC + CONVD + NH + h * NLV + l]);
}

// ---------------- per-head inclusive cumsum of g over t ----------------
__global__ __launch_bounds__(1024) void scan_kernel(const float* __restrict__ g_ht,
                                                    float* __restrict__ gc) {
  __shared__ float buf[1024];
  int h = blockIdx.x, t = threadIdx.x;
  buf[t] = g_ht[h * T_LEN + t];
  __syncthreads();
  for (int off = 1; off < 1024; off <<= 1) {
    float add = (t >= off) ? buf[t - off] : 0.f;
    __syncthreads();
    buf[t] += add;
    __syncthreads();
  }
  gc[h * T_LEN + t] = buf[t];
}

// ------- conv(K=4)+SiLU; writes x(f32), v^T hi/lo(bf16), B/C hi/lo -------
__global__ __launch_bounds__(256) void conv_kernel(const float* __restrict__ zx,
    const float* __restrict__ convw, const float* __restrict__ dt,
    float* __restrict__ xout,
    unsigned short* __restrict__ vth, unsigned short* __restrict__ vtl,
    unsigned short* __restrict__ Bmh, unsigned short* __restrict__ Bml,
    unsigned short* __restrict__ Cmh, unsigned short* __restrict__ Cml) {
  __shared__ float tile[64][65];
  const int c0 = blockIdx.x * 64, t0 = blockIdx.y * 64;
  const int cl = threadIdx.x & 63, q = threadIdx.x >> 6;
  const int c = c0 + cl;
  const float4 wv = *(const float4*)(convw + c * 4);
  const float warr[4] = {wv.x, wv.y, wv.z, wv.w};
#pragma unroll
  for (int it = 0; it < 16; ++it) {
    int tt = it * 4 + q;
    int t = t0 + tt;
    float acc = 0.f;
#pragma unroll
    for (int i = 0; i < 4; ++i) {
      int ts = t - 3 + i;
      if (ts >= 0) acc += zx[(size_t)ts * PROJ_C + DIMC + c] * warr[i];
    }
    float val = acc / (1.f + __expf(-acc));
    if (c < DIMC) {
      xout[(size_t)t * DIMC + c] = val;
      tile[tt][cl] = val;  // tile[time_local][chan_local]
    } else if (c < DIMC + DST) {
      short hi = f2bf(val);
      Bmh[t * DST + (c - DIMC)] = (unsigned short)hi;
      Bml[t * DST + (c - DIMC)] = (unsigned short)f2bf(val - bf2f(hi));
    } else {
      short hi = f2bf(val);
      Cmh[t * DST + (c - DIMC - DST)] = (unsigned short)hi;
      Cml[t * DST + (c - DIMC - DST)] = (unsigned short)f2bf(val - bf2f(hi));
    }
  }
  if (c0 < DIMC) {
    __syncthreads();
    const int tl = threadIdx.x & 63;
    const int t = t0 + tl;
#pragma unroll
    for (int it = 0; it < 16; ++it) {
      int cc = it * 4 + q;
      int c2 = c0 + cc;
      int h = c2 >> 6;
      float vv = tile[tl][cc] * dt[t * NH + h];  // v[t][c2], transpose-read
      short hi = f2bf(vv);
      vth[(size_t)c2 * T_LEN + t] = (unsigned short)hi;
      vtl[(size_t)c2 * T_LEN + t] = (unsigned short)f2bf(vv - bf2f(hi));
    }
  }
}

// ------- attention MFMA, compensated + LDS XOR-swizzled v tiles -------
__global__ __launch_bounds__(256) void attn_mfma(const float* __restrict__ qkf,
    const unsigned short* __restrict__ vth, const unsigned short* __restrict__ vtl,
    const float* __restrict__ gc, const float* __restrict__ lam,
    const float* __restrict__ xf, const float* __restrict__ Dv, float* __restrict__ y) {
  __shared__ __align__(16) unsigned short vth_lds[64 * 64];
  __shared__ __align__(16) unsigned short vtl_lds[64 * 64];
  __shared__ float gcs[64];
  __shared__ float lam_lds[64][17];
  const int h = blockIdx.y;
  const int ttile = gridDim.x - 1 - blockIdx.x;  // heavy blocks dispatched first
  const int t0 = ttile * 64;
  const int tid = threadIdx.x;
  const int lane = tid & 63, wave = tid >> 6;
  const int lrow = lane & 15, lgrp = lane >> 4;
  const int tglob = t0 + wave * 16 + lrow;

  for (int i = tid; i < 64 * NLV; i += 256) {
    int tl = i / NLV, l = i - tl * NLV;
    lam_lds[tl][l] = lam[((size_t)(t0 + tl) * NH + h) * NLV + l];
  }
  const float gct = gc[h * T_LEN + tglob];
  const float Dh = Dv[h];
  f32x4 zero4 = {0.f, 0.f, 0.f, 0.f};
  f32x4 acc[4];
  for (int j = 0; j < 4; ++j) acc[j] = zero4;

  const int nsb = ttile + 1;
  for (int sb = 0; sb < nsb; ++sb) {
    int s0 = sb * 64;
#pragma unroll
    for (int it = 0; it < 2; ++it) {
      int idx = it * 256 + tid;
      int p = idx >> 3, cb = idx & 7;
      int ds = (cb ^ (p & 7)) * 8;   // pre-swizzled source col
      gload16(vth + (size_t)(h * 64 + p) * T_LEN + s0 + ds, vth_lds + it * 2048 + wave * 512);
      gload16(vtl + (size_t)(h * 64 + p) * T_LEN + s0 + ds, vtl_lds + it * 2048 + wave * 512);
    }
    if (tid < 64) gcs[tid] = gc[h * T_LEN + s0 + tid];
    __syncthreads();
#pragma unroll
    for (int kk = 0; kk < 2; ++kk) {
      int sbase = s0 + kk * 32 + lgrp * 8;
      float4 q1 = *(const float4*)(qkf + (size_t)tglob * T_LEN + sbase);
      float4 q2 = *(const float4*)(qkf + (size_t)tglob * T_LEN + sbase + 4);
      float qv[8] = {q1.x, q1.y, q1.z, q1.w, q2.x, q2.y, q2.z, q2.w};
      bf16x8 ah, al;
#pragma unroll
      for (int e2 = 0; e2 < 8; ++e2) {
        int s = sbase + e2;
        float w = 0.f;
        if (s <= tglob) {
          float dec = __expf(gct - gcs[s - s0]);
          int lvl = (s == tglob) ? 0 : (32 - __clz(s ^ tglob));
          w = qv[e2] * dec * lam_lds[tglob - t0][lvl];
        }
        short hi = f2bf(w);
        ah[e2] = hi;
        al[e2] = f2bf(w - bf2f(hi));
      }
#pragma unroll
      for (int j = 0; j < 4; ++j) {
        int row = j * 16 + lrow;
        int o = row * 64 + (((kk * 4 + lgrp) ^ (row & 7)) * 8);
        bf16x8 bh = *(const bf16x8*)(vth_lds + o);
        bf16x8 bl = *(const bf16x8*)(vtl_lds + o);
        acc[j] = __builtin_amdgcn_mfma_f32_16x16x32_bf16(al, bh, acc[j], 0, 0, 0);
        acc[j] = __builtin_amdgcn_mfma_f32_16x16x32_bf16(ah, bl, acc[j], 0, 0, 0);
        acc[j] = __builtin_amdgcn_mfma_f32_16x16x32_bf16(ah, bh, acc[j], 0, 0, 0);
      }
    }
    __syncthreads();
  }
#pragma unroll
  for (int j = 0; j < 4; ++j) {
    int p = j * 16 + lrow;
    int cc = h * 64 + p;
#pragma unroll
    for (int r = 0; r < 4; ++r) {
      int t = t0 + wave * 16 + lgrp * 4 + r;
      y[(size_t)t * DIMC + cc] = acc[j][r] + xf[(size_t)t * DIMC + cc] * Dh;
    }
  }
}

// ------- gate (y * silu(z)) + RMSNorm -> bf16 hi/lo -------
__global__ __launch_bounds__(256) void gate_rms(const float* __restrict__ y,
    const float* __restrict__ zx, const float* __restrict__ nw,
    unsigned short* __restrict__ outh, unsigned short* __restrict__ outl) {
  const int t = blockIdx.x;
  const float* yr = y + (size_t)t * DIMC;
  const float* zr = zx + (size_t)t * PROJ_C;
  float vals[8];
  float ss = 0.f;
#pragma unroll
  for (int i = 0; i < 8; ++i) {
    int cidx = i * 256 + threadIdx.x;
    float z = zr[cidx];
    float yz = yr[cidx] * (z / (1.f + __expf(-z)));
    vals[i] = yz;
    ss += yz * yz;
  }
#pragma unroll
  for (int off = 32; off > 0; off >>= 1) ss += __shfl_xor(ss, off, 64);
  __shared__ float red[4];
  if ((threadIdx.x & 63) == 0) red[threadIdx.x >> 6] = ss;
  __syncthreads();
  float tot = red[0] + red[1] + red[2] + red[3];
  float rs = rsqrtf(tot * (1.f / DIMC) + 1e-5f);
#pragma unroll
  for (int i = 0; i < 8; ++i) {
    int cidx = i * 256 + threadIdx.x;
    float v = vals[i] * rs * nw[cidx];
    short hi = f2bf(v);
    outh[(size_t)t * DIMC + cidx] = (unsigned short)hi;
    outl[(size_t)t * DIMC + cidx] = (unsigned short)f2bf(v - bf2f(hi));
  }
}

extern "C" void kernel_launch(void* const* d_in, const int* in_sizes, int n_in,
                              void* d_out, int out_size, void* d_ws, size_t ws_size,
                              hipStream_t stream) {
  const float* hs   = (const float*)d_in[0];
  const float* w1   = (const float*)d_in[1];
  const float* b1   = (const float*)d_in[2];
  const float* cw   = (const float*)d_in[3];
  const float* dtb  = (const float*)d_in[4];
  const float* alog = (const float*)d_in[5];
  const float* Lm   = (const float*)d_in[6];
  const float* Dv   = (const float*)d_in[7];
  const float* nw   = (const float*)d_in[8];
  const float* w3   = (const float*)d_in[9];
  const float* b3   = (const float*)d_in[10];
  float* out = (float*)d_out;

  char* base = (char*)d_ws;
  size_t off = 0;
  auto alloc = [&](size_t b) {
    void* r = base + off;
    off = (off + b + 255) & ~(size_t)255;
    return r;
  };
  unsigned short* hs_h = (unsigned short*)alloc((size_t)T_LEN * HID * 2);
  unsigned short* hs_l = (unsigned short*)alloc((size_t)T_LEN * HID * 2);
  unsigned short* w1_h = (unsigned short*)alloc((size_t)PROJ_C * HID * 2);
  unsigned short* w1_l = (unsigned short*)alloc((size_t)PROJ_C * HID * 2);
  unsigned short* w3_h = (unsigned short*)alloc((size_t)HID * DIMC * 2);
  unsigned short* w3_l = (unsigned short*)alloc((size_t)HID * DIMC * 2);
  float* zx   = (float*)alloc((size_t)T_LEN * PROJ_C * 4);
  float* dt   = (float*)alloc((size_t)T_LEN * NH * 4);
  float* g_ht = (float*)alloc((size_t)NH * T_LEN * 4);
  float* gc   = (float*)alloc((size_t)NH * T_LEN * 4);
  float* lam  = (float*)alloc((size_t)T_LEN * NH * NLV * 4);
  float* xf   = (float*)alloc((size_t)T_LEN * DIMC * 4);
  unsigned short* vth = (unsigned short*)alloc((size_t)DIMC * T_LEN * 2);
  unsigned short* vtl = (unsigned short*)alloc((size_t)DIMC * T_LEN * 2);
  unsigned short* Bmh = (unsigned short*)alloc((size_t)T_LEN * DST * 2);
  unsigned short* Bml = (unsigned short*)alloc((size_t)T_LEN * DST * 2);
  unsigned short* Cmh = (unsigned short*)alloc((size_t)T_LEN * DST * 2);
  unsigned short* Cml = (unsigned short*)alloc((size_t)T_LEN * DST * 2);
  float* qkf = (float*)alloc((size_t)T_LEN * T_LEN * 4);
  float* y = (float*)alloc((size_t)T_LEN * DIMC * 4);
  unsigned short* nbh = (unsigned short*)alloc((size_t)T_LEN * DIMC * 2);
  unsigned short* nbl = (unsigned short*)alloc((size_t)T_LEN * DIMC * 2);

  int n1 = T_LEN * HID;
  int n2 = PROJ_C * HID;
  int n3 = HID * DIMC;
  cast_split_kernel<<<(n1 / 4 + 255) / 256, 256, 0, stream>>>(hs, hs_h, hs_l, n1);
  cast_split_kernel<<<(n2 / 4 + 255) / 256, 256, 0, stream>>>(w1, w1_h, w1_l, n2);
  cast_split_kernel<<<(n3 / 4 + 255) / 256, 256, 0, stream>>>(w3, w3_h, w3_l, n3);

  // zx = hs*w1^T + b1 (f32-equivalent), 76x16 = 1216 blocks
  gemm64_comp<1, 0><<<dim3(PROJ_C / 64, T_LEN / 64), 256, 0, stream>>>(
      hs_h, hs_l, w1_h, w1_l, b1, zx, T_LEN, PROJ_C, HID);

  scalar_kernel<<<(T_LEN * NH) / 256, 256, 0, stream>>>(zx, dtb, alog, Lm, dt, g_ht, lam);
  scan_kernel<<<NH, 1024, 0, stream>>>(g_ht, gc);
  conv_kernel<<<dim3(CONVD / 64, T_LEN / 64), 256, 0, stream>>>(
      zx, cw, dt, xf, vth, vtl, Bmh, Bml, Cmh, Cml);

  // qk = C*B^T, 16x16 = 256 blocks
  gemm64_comp<0, 0><<<dim3(T_LEN / 64, T_LEN / 64), 256, 0, stream>>>(
      Cmh, Cml, Bmh, Bml, nullptr, qkf, T_LEN, T_LEN, DST);

  attn_mfma<<<dim3(T_LEN / 64, NH), 256, 0, stream>>>(qkf, vth, vtl, gc, lam, xf, Dv, y);
  gate_rms<<<T_LEN, 256, 0, stream>>>(y, zx, nw, nbh, nbl);

  // out = nb*w3^T + b3: split-K x4 -> 16x16x4 = 1024 blocks, atomicAdd into zeroed out
  hipMemsetAsync(out, 0, (size_t)out_size * 4, stream);
  gemm64_comp<1, 1><<<dim3(HID / 64, T_LEN / 64, 4), 256, 0, stream>>>(
      nbh, nbl, w3_h, w3_l, b3, out, T_LEN, HID, DIMC);
}

// Round 13
// 257.670 us; speedup vs baseline: 2.3674x; 1.0402x over previous
//
#include <hip/hip_runtime.h>
#include <hip/hip_bf16.h>

#define T_LEN 1024
#define HID 1024
#define NH 32
#define HD 64
#define DIMC 2048
#define CONVD 2304
#define PROJ_C 4864
#define DST 128
#define NLV 15
#define ATT_NS 4

typedef __attribute__((ext_vector_type(8))) short bf16x8;
typedef __attribute__((ext_vector_type(4))) float f32x4;

__device__ __forceinline__ float bf2f(short s) {
  unsigned u = ((unsigned)(unsigned short)s) << 16;
  return __builtin_bit_cast(float, u);
}
__device__ __forceinline__ short f2bf(float f) {
  return __builtin_bit_cast(short, __float2bfloat16(f));
}
__device__ __forceinline__ void gload16(const void* g, void* l) {
  __builtin_amdgcn_global_load_lds((const __attribute__((address_space(1))) unsigned int*)g,
                                   (__attribute__((address_space(3))) unsigned int*)l, 16, 0, 0);
}
__device__ __forceinline__ float softplus_f(float x) {
  return (x > 15.f) ? x : log1pf(expf(x));
}

// ---------------- split f32 -> bf16 hi + lo (Dekker) ----------------
__global__ void cast_split_kernel(const float* __restrict__ in,
    unsigned short* __restrict__ hi, unsigned short* __restrict__ lo, int n) {
  int i = (blockIdx.x * 256 + threadIdx.x) * 4;
  if (i >= n) return;
  float4 v = *(const float4*)(in + i);
  ushort4 h, l;
  h.x = (unsigned short)f2bf(v.x); l.x = (unsigned short)f2bf(v.x - bf2f((short)h.x));
  h.y = (unsigned short)f2bf(v.y); l.y = (unsigned short)f2bf(v.y - bf2f((short)h.y));
  h.z = (unsigned short)f2bf(v.z); l.z = (unsigned short)f2bf(v.z - bf2f((short)h.z));
  h.w = (unsigned short)f2bf(v.w); l.w = (unsigned short)f2bf(v.w - bf2f((short)h.w));
  *(ushort4*)(hi + i) = h;
  *(ushort4*)(lo + i) = l;
}

// ------- 64x64-tile fused compensated bf16 GEMM, LDS XOR-swizzled -------
template<int HAS_BIAS, int ATOMIC>
__global__ __launch_bounds__(256) void gemm64_comp(
    const unsigned short* __restrict__ Ah, const unsigned short* __restrict__ Al,
    const unsigned short* __restrict__ Bh, const unsigned short* __restrict__ Bl,
    const float* __restrict__ bias, float* __restrict__ C, int M, int N, int K) {
  __shared__ __align__(16) unsigned short Ash[64 * 64];
  __shared__ __align__(16) unsigned short Asl[64 * 64];
  __shared__ __align__(16) unsigned short Bsh[64 * 64];
  __shared__ __align__(16) unsigned short Bsl[64 * 64];
  const int tid = threadIdx.x;
  const int lane = tid & 63, wave = tid >> 6;
  const int wm = wave >> 1, wn = wave & 1;
  const int lrow = lane & 15, lgrp = lane >> 4;
  const int row0 = blockIdx.y * 64, col0 = blockIdx.x * 64;
  int k0beg = 0, k0end = K;
  if (ATOMIC) {
    int kc = K / gridDim.z;
    k0beg = blockIdx.z * kc;
    k0end = k0beg + kc;
  }
  f32x4 zero4 = {0.f, 0.f, 0.f, 0.f};
  f32x4 acc[2][2];
  for (int i = 0; i < 2; ++i) for (int j = 0; j < 2; ++j) acc[i][j] = zero4;

  for (int k0 = k0beg; k0 < k0end; k0 += 64) {
#pragma unroll
    for (int it = 0; it < 2; ++it) {
      int idx = it * 256 + tid;      // staged 16B-block index = r*8 + cb
      int r = idx >> 3, cb = idx & 7;
      int c = (cb ^ (r & 7)) * 8;    // pre-swizzled source col
      gload16(Ah + (size_t)(row0 + r) * K + k0 + c, Ash + it * 2048 + wave * 512);
      gload16(Al + (size_t)(row0 + r) * K + k0 + c, Asl + it * 2048 + wave * 512);
      gload16(Bh + (size_t)(col0 + r) * K + k0 + c, Bsh + it * 2048 + wave * 512);
      gload16(Bl + (size_t)(col0 + r) * K + k0 + c, Bsl + it * 2048 + wave * 512);
    }
    __syncthreads();
#pragma unroll
    for (int kk = 0; kk < 2; ++kk) {
      bf16x8 afh[2], afl[2], bfh[2], bfl[2];
#pragma unroll
      for (int i = 0; i < 2; ++i) {
        int row = wm * 32 + i * 16 + lrow;
        int o = row * 64 + (((kk * 4 + lgrp) ^ (row & 7)) * 8);
        afh[i] = *(const bf16x8*)(Ash + o);
        afl[i] = *(const bf16x8*)(Asl + o);
      }
#pragma unroll
      for (int j = 0; j < 2; ++j) {
        int row = wn * 32 + j * 16 + lrow;
        int o = row * 64 + (((kk * 4 + lgrp) ^ (row & 7)) * 8);
        bfh[j] = *(const bf16x8*)(Bsh + o);
        bfl[j] = *(const bf16x8*)(Bsl + o);
      }
#pragma unroll
      for (int i = 0; i < 2; ++i)
#pragma unroll
        for (int j = 0; j < 2; ++j) {
          acc[i][j] = __builtin_amdgcn_mfma_f32_16x16x32_bf16(afl[i], bfh[j], acc[i][j], 0, 0, 0);
          acc[i][j] = __builtin_amdgcn_mfma_f32_16x16x32_bf16(afh[i], bfl[j], acc[i][j], 0, 0, 0);
          acc[i][j] = __builtin_amdgcn_mfma_f32_16x16x32_bf16(afh[i], bfh[j], acc[i][j], 0, 0, 0);
        }
    }
    __syncthreads();
  }

#pragma unroll
  for (int i = 0; i < 2; ++i) {
#pragma unroll
    for (int j = 0; j < 2; ++j) {
      int col = col0 + wn * 32 + j * 16 + lrow;
      float bv = (HAS_BIAS && (!ATOMIC || blockIdx.z == 0)) ? bias[col] : 0.f;
#pragma unroll
      for (int r = 0; r < 2 * 2; ++r) {
        int row = row0 + wm * 32 + i * 16 + lgrp * 4 + r;
        float v = acc[i][j][r] + bv;
        if (ATOMIC) atomicAdd(&C[(size_t)row * N + col], v);
        else        C[(size_t)row * N + col] = v;
      }
    }
  }
}

// ---------------- per-(t,h) scalars: dt, g, lambda ----------------
__global__ void scalar_kernel(const float* __restrict__ zx, const float* __restrict__ dtb,
    const float* __restrict__ alog, const float* __restrict__ Lm,
    float* __restrict__ dt, float* __restrict__ g_ht, float* __restrict__ lam) {
  int idx = blockIdx.x * 256 + threadIdx.x;
  if (idx >= T_LEN * NH) return;
  int t = idx >> 5, h = idx & 31;
  const float* row = zx + (size_t)t * PROJ_C;
  float dv = softplus_f(row[DIMC + CONVD + h] + dtb[h]);
  dt[t * NH + h] = dv;
  g_ht[h * T_LEN + t] = -expf(alog[h]) * dv;
#pragma unroll
  for (int l = 0; l < NLV; ++l)
    lam[((size_t)t * NH + h) * NLV + l] =
        softplus_f(Lm[h * NLV + l] * row[DIMC + CONVD + NH + h * NLV + l]);
}

// ---------------- per-head inclusive cumsum of g over t ----------------
__global__ __launch_bounds__(1024) void scan_kernel(const float* __restrict__ g_ht,
                                                    float* __restrict__ gc) {
  __shared__ float buf[1024];
  int h = blockIdx.x, t = threadIdx.x;
  buf[t] = g_ht[h * T_LEN + t];
  __syncthreads();
  for (int off = 1; off < 1024; off <<= 1) {
    float add = (t >= off) ? buf[t - off] : 0.f;
    __syncthreads();
    buf[t] += add;
    __syncthreads();
  }
  gc[h * T_LEN + t] = buf[t];
}

// ------- conv(K=4)+SiLU; writes x(f32), v^T hi/lo(bf16), B/C hi/lo -------
__global__ __launch_bounds__(256) void conv_kernel(const float* __restrict__ zx,
    const float* __restrict__ convw, const float* __restrict__ dt,
    float* __restrict__ xout,
    unsigned short* __restrict__ vth, unsigned short* __restrict__ vtl,
    unsigned short* __restrict__ Bmh, unsigned short* __restrict__ Bml,
    unsigned short* __restrict__ Cmh, unsigned short* __restrict__ Cml) {
  __shared__ float tile[64][65];
  const int c0 = blockIdx.x * 64, t0 = blockIdx.y * 64;
  const int cl = threadIdx.x & 63, q = threadIdx.x >> 6;
  const int c = c0 + cl;
  const float4 wv = *(const float4*)(convw + c * 4);
  const float warr[4] = {wv.x, wv.y, wv.z, wv.w};
#pragma unroll
  for (int it = 0; it < 16; ++it) {
    int tt = it * 4 + q;
    int t = t0 + tt;
    float acc = 0.f;
#pragma unroll
    for (int i = 0; i < 4; ++i) {
      int ts = t - 3 + i;
      if (ts >= 0) acc += zx[(size_t)ts * PROJ_C + DIMC + c] * warr[i];
    }
    float val = acc / (1.f + __expf(-acc));
    if (c < DIMC) {
      xout[(size_t)t * DIMC + c] = val;
      tile[tt][cl] = val;  // tile[time_local][chan_local]
    } else if (c < DIMC + DST) {
      short hi = f2bf(val);
      Bmh[t * DST + (c - DIMC)] = (unsigned short)hi;
      Bml[t * DST + (c - DIMC)] = (unsigned short)f2bf(val - bf2f(hi));
    } else {
      short hi = f2bf(val);
      Cmh[t * DST + (c - DIMC - DST)] = (unsigned short)hi;
      Cml[t * DST + (c - DIMC - DST)] = (unsigned short)f2bf(val - bf2f(hi));
    }
  }
  if (c0 < DIMC) {
    __syncthreads();
    const int tl = threadIdx.x & 63;
    const int t = t0 + tl;
#pragma unroll
    for (int it = 0; it < 16; ++it) {
      int cc = it * 4 + q;
      int c2 = c0 + cc;
      int h = c2 >> 6;
      float vv = tile[tl][cc] * dt[t * NH + h];  // v[t][c2], transpose-read
      short hi = f2bf(vv);
      vth[(size_t)c2 * T_LEN + t] = (unsigned short)hi;
      vtl[(size_t)c2 * T_LEN + t] = (unsigned short)f2bf(vv - bf2f(hi));
    }
  }
}

// ------- attention MFMA, compensated, split-s over grid.z, atomicAdd into y -------
__global__ __launch_bounds__(256) void attn_mfma(const float* __restrict__ qkf,
    const unsigned short* __restrict__ vth, const unsigned short* __restrict__ vtl,
    const float* __restrict__ gc, const float* __restrict__ lam,
    float* __restrict__ y) {
  __shared__ __align__(16) unsigned short vth_lds[64 * 64];
  __shared__ __align__(16) unsigned short vtl_lds[64 * 64];
  __shared__ float gcs[64];
  __shared__ float lam_lds[64][17];
  const int h = blockIdx.y;
  const int ttile = gridDim.x - 1 - blockIdx.x;  // heavy blocks dispatched first
  const int z = blockIdx.z;
  if (z > ttile) return;                          // block-uniform early exit
  const int t0 = ttile * 64;
  const int tid = threadIdx.x;
  const int lane = tid & 63, wave = tid >> 6;
  const int lrow = lane & 15, lgrp = lane >> 4;
  const int tglob = t0 + wave * 16 + lrow;

  for (int i = tid; i < 64 * NLV; i += 256) {
    int tl = i / NLV, l = i - tl * NLV;
    lam_lds[tl][l] = lam[((size_t)(t0 + tl) * NH + h) * NLV + l];
  }
  const float gct = gc[h * T_LEN + tglob];
  f32x4 zero4 = {0.f, 0.f, 0.f, 0.f};
  f32x4 acc[4];
  for (int j = 0; j < 4; ++j) acc[j] = zero4;

  for (int sb = z; sb <= ttile; sb += ATT_NS) {
    int s0 = sb * 64;
#pragma unroll
    for (int it = 0; it < 2; ++it) {
      int idx = it * 256 + tid;
      int p = idx >> 3, cb = idx & 7;
      int ds = (cb ^ (p & 7)) * 8;   // pre-swizzled source col
      gload16(vth + (size_t)(h * 64 + p) * T_LEN + s0 + ds, vth_lds + it * 2048 + wave * 512);
      gload16(vtl + (size_t)(h * 64 + p) * T_LEN + s0 + ds, vtl_lds + it * 2048 + wave * 512);
    }
    if (tid < 64) gcs[tid] = gc[h * T_LEN + s0 + tid];
    __syncthreads();
#pragma unroll
    for (int kk = 0; kk < 2; ++kk) {
      int sbase = s0 + kk * 32 + lgrp * 8;
      float4 q1 = *(const float4*)(qkf + (size_t)tglob * T_LEN + sbase);
      float4 q2 = *(const float4*)(qkf + (size_t)tglob * T_LEN + sbase + 4);
      float qv[8] = {q1.x, q1.y, q1.z, q1.w, q2.x, q2.y, q2.z, q2.w};
      bf16x8 ah, al;
#pragma unroll
      for (int e2 = 0; e2 < 8; ++e2) {
        int s = sbase + e2;
        float w = 0.f;
        if (s <= tglob) {
          float dec = __expf(gct - gcs[s - s0]);
          int lvl = (s == tglob) ? 0 : (32 - __clz(s ^ tglob));
          w = qv[e2] * dec * lam_lds[tglob - t0][lvl];
        }
        short hi = f2bf(w);
        ah[e2] = hi;
        al[e2] = f2bf(w - bf2f(hi));
      }
#pragma unroll
      for (int j = 0; j < 4; ++j) {
        int row = j * 16 + lrow;
        int o = row * 64 + (((kk * 4 + lgrp) ^ (row & 7)) * 8);
        bf16x8 bh = *(const bf16x8*)(vth_lds + o);
        bf16x8 bl = *(const bf16x8*)(vtl_lds + o);
        acc[j] = __builtin_amdgcn_mfma_f32_16x16x32_bf16(al, bh, acc[j], 0, 0, 0);
        acc[j] = __builtin_amdgcn_mfma_f32_16x16x32_bf16(ah, bl, acc[j], 0, 0, 0);
        acc[j] = __builtin_amdgcn_mfma_f32_16x16x32_bf16(ah, bh, acc[j], 0, 0, 0);
      }
    }
    __syncthreads();
  }
#pragma unroll
  for (int j = 0; j < 4; ++j) {
    int p = j * 16 + lrow;
    int cc = h * 64 + p;
#pragma unroll
    for (int r = 0; r < 4; ++r) {
      int t = t0 + wave * 16 + lgrp * 4 + r;
      atomicAdd(&y[(size_t)t * DIMC + cc], acc[j][r]);
    }
  }
}

// ------- gate ((y + D*x) * silu(z)) + RMSNorm -> bf16 hi/lo -------
__global__ __launch_bounds__(256) void gate_rms(const float* __restrict__ y,
    const float* __restrict__ zx, const float* __restrict__ xf,
    const float* __restrict__ Dv, const float* __restrict__ nw,
    unsigned short* __restrict__ outh, unsigned short* __restrict__ outl) {
  const int t = blockIdx.x;
  const float* yr = y + (size_t)t * DIMC;
  const float* xr = xf + (size_t)t * DIMC;
  const float* zr = zx + (size_t)t * PROJ_C;
  float vals[8];
  float ss = 0.f;
#pragma unroll
  for (int i = 0; i < 8; ++i) {
    int cidx = i * 256 + threadIdx.x;
    float z = zr[cidx];
    float yv = yr[cidx] + Dv[cidx >> 6] * xr[cidx];
    float yz = yv * (z / (1.f + __expf(-z)));
    vals[i] = yz;
    ss += yz * yz;
  }
#pragma unroll
  for (int off = 32; off > 0; off >>= 1) ss += __shfl_xor(ss, off, 64);
  __shared__ float red[4];
  if ((threadIdx.x & 63) == 0) red[threadIdx.x >> 6] = ss;
  __syncthreads();
  float tot = red[0] + red[1] + red[2] + red[3];
  float rs = rsqrtf(tot * (1.f / DIMC) + 1e-5f);
#pragma unroll
  for (int i = 0; i < 8; ++i) {
    int cidx = i * 256 + threadIdx.x;
    float v = vals[i] * rs * nw[cidx];
    short hi = f2bf(v);
    outh[(size_t)t * DIMC + cidx] = (unsigned short)hi;
    outl[(size_t)t * DIMC + cidx] = (unsigned short)f2bf(v - bf2f(hi));
  }
}

extern "C" void kernel_launch(void* const* d_in, const int* in_sizes, int n_in,
                              void* d_out, int out_size, void* d_ws, size_t ws_size,
                              hipStream_t stream) {
  const float* hs   = (const float*)d_in[0];
  const float* w1   = (const float*)d_in[1];
  const float* b1   = (const float*)d_in[2];
  const float* cw   = (const float*)d_in[3];
  const float* dtb  = (const float*)d_in[4];
  const float* alog = (const float*)d_in[5];
  const float* Lm   = (const float*)d_in[6];
  const float* Dv   = (const float*)d_in[7];
  const float* nw   = (const float*)d_in[8];
  const float* w3   = (const float*)d_in[9];
  const float* b3   = (const float*)d_in[10];
  float* out = (float*)d_out;

  char* base = (char*)d_ws;
  size_t off = 0;
  auto alloc = [&](size_t b) {
    void* r = base + off;
    off = (off + b + 255) & ~(size_t)255;
    return r;
  };
  unsigned short* hs_h = (unsigned short*)alloc((size_t)T_LEN * HID * 2);
  unsigned short* hs_l = (unsigned short*)alloc((size_t)T_LEN * HID * 2);
  unsigned short* w1_h = (unsigned short*)alloc((size_t)PROJ_C * HID * 2);
  unsigned short* w1_l = (unsigned short*)alloc((size_t)PROJ_C * HID * 2);
  unsigned short* w3_h = (unsigned short*)alloc((size_t)HID * DIMC * 2);
  unsigned short* w3_l = (unsigned short*)alloc((size_t)HID * DIMC * 2);
  float* zx   = (float*)alloc((size_t)T_LEN * PROJ_C * 4);
  float* dt   = (float*)alloc((size_t)T_LEN * NH * 4);
  float* g_ht = (float*)alloc((size_t)NH * T_LEN * 4);
  float* gc   = (float*)alloc((size_t)NH * T_LEN * 4);
  float* lam  = (float*)alloc((size_t)T_LEN * NH * NLV * 4);
  float* xf   = (float*)alloc((size_t)T_LEN * DIMC * 4);
  unsigned short* vth = (unsigned short*)alloc((size_t)DIMC * T_LEN * 2);
  unsigned short* vtl = (unsigned short*)alloc((size_t)DIMC * T_LEN * 2);
  unsigned short* Bmh = (unsigned short*)alloc((size_t)T_LEN * DST * 2);
  unsigned short* Bml = (unsigned short*)alloc((size_t)T_LEN * DST * 2);
  unsigned short* Cmh = (unsigned short*)alloc((size_t)T_LEN * DST * 2);
  unsigned short* Cml = (unsigned short*)alloc((size_t)T_LEN * DST * 2);
  float* qkf = (float*)alloc((size_t)T_LEN * T_LEN * 4);
  float* y = (float*)alloc((size_t)T_LEN * DIMC * 4);
  unsigned short* nbh = (unsigned short*)alloc((size_t)T_LEN * DIMC * 2);
  unsigned short* nbl = (unsigned short*)alloc((size_t)T_LEN * DIMC * 2);

  int n1 = T_LEN * HID;
  int n2 = PROJ_C * HID;
  int n3 = HID * DIMC;
  cast_split_kernel<<<(n1 / 4 + 255) / 256, 256, 0, stream>>>(hs, hs_h, hs_l, n1);
  cast_split_kernel<<<(n2 / 4 + 255) / 256, 256, 0, stream>>>(w1, w1_h, w1_l, n2);
  cast_split_kernel<<<(n3 / 4 + 255) / 256, 256, 0, stream>>>(w3, w3_h, w3_l, n3);

  // zx = hs*w1^T + b1 (f32-equivalent), 76x16 = 1216 blocks
  gemm64_comp<1, 0><<<dim3(PROJ_C / 64, T_LEN / 64), 256, 0, stream>>>(
      hs_h, hs_l, w1_h, w1_l, b1, zx, T_LEN, PROJ_C, HID);

  scalar_kernel<<<(T_LEN * NH) / 256, 256, 0, stream>>>(zx, dtb, alog, Lm, dt, g_ht, lam);
  scan_kernel<<<NH, 1024, 0, stream>>>(g_ht, gc);
  conv_kernel<<<dim3(CONVD / 64, T_LEN / 64), 256, 0, stream>>>(
      zx, cw, dt, xf, vth, vtl, Bmh, Bml, Cmh, Cml);

  // qk = C*B^T, 16x16 = 256 blocks
  gemm64_comp<0, 0><<<dim3(T_LEN / 64, T_LEN / 64), 256, 0, stream>>>(
      Cmh, Cml, Bmh, Bml, nullptr, qkf, T_LEN, T_LEN, DST);

  // attention: split-s x4, partials atomically accumulated into zeroed y
  hipMemsetAsync(y, 0, (size_t)T_LEN * DIMC * 4, stream);
  attn_mfma<<<dim3(T_LEN / 64, NH, ATT_NS), 256, 0, stream>>>(qkf, vth, vtl, gc, lam, y);

  gate_rms<<<T_LEN, 256, 0, stream>>>(y, zx, xf, Dv, nw, nbh, nbl);

  // out = nb*w3^T + b3: split-K x4 -> 16x16x4 = 1024 blocks, atomicAdd into zeroed out
  hipMemsetAsync(out, 0, (size_t)out_size * 4, stream);
  gemm64_comp<1, 1><<<dim3(HID / 64, T_LEN / 64, 4), 256, 0, stream>>>(
      nbh, nbl, w3_h, w3_l, b3, out, T_LEN, HID, DIMC);
}